// Round 10
// baseline (1295.467 us; speedup 1.0000x reference)
//
#include <hip/hip_runtime.h>
#include <hip/hip_bf16.h>
#include <math.h>

#define NNODE 65536
#define NBAT  16384
#define NP    5
#define DT    0.1f
#define EPS   1e-5f

typedef __attribute__((ext_vector_type(8))) short short8;
typedef __attribute__((ext_vector_type(4))) float floatx4;

union S8U { short8 s; unsigned int u[4]; };

// fast swish: x * rcp(1+e^-x)
__device__ __forceinline__ float swishf(float x) {
    return x * __builtin_amdgcn_rcpf(1.f + __expf(-x));
}
__device__ __forceinline__ float asf(unsigned int u) {
    union { unsigned int u; float f; } x; x.u = u; return x.f;
}
__device__ __forceinline__ unsigned short f2b(float f) {
    union { float f; unsigned int u; } x; x.f = f;
    unsigned int r = x.u + 0x7fff + ((x.u >> 16) & 1);
    return (unsigned short)(r >> 16);
}
__device__ __forceinline__ unsigned int pk2(float a, float b) {
    __hip_bfloat162 h = __float22bfloat162_rn(make_float2(a, b));
    union { __hip_bfloat162 h; unsigned int u; } x; x.h = h; return x.u;
}

// padded fragment chunk offset (in shorts)
#define CHP(w, g, r15) ((((w) * 272) + (g) * 17 + (r15)) * 8)

// ---------- fused weight prep: all matrices in one launch ----------
__global__ __launch_bounds__(256) void prep_all(
    const float* __restrict__ msg1_W, const float* __restrict__ msg2_W,
    const float* __restrict__ upd1_W, const float* __restrict__ upd2_W,
    const float* __restrict__ emb_W2, const float* __restrict__ out_W1,
    unsigned short* __restrict__ wPT, unsigned short* __restrict__ wQT,
    unsigned short* __restrict__ w2F, unsigned short* __restrict__ u1aF,
    unsigned short* __restrict__ u1bF, unsigned short* __restrict__ u2F,
    unsigned short* __restrict__ eW2F, unsigned short* __restrict__ O1F)
{
    int blk = blockIdx.x;
    const float* src; unsigned short* dst;
    int ldn = 128, koff, NT = 8, lstride, perm = 1, i0;
    if (blk < 384)       { src = msg1_W; dst = wPT;  koff = 0;   lstride = 264 * 128; i0 = blk; }
    else if (blk < 768)  { src = msg1_W; dst = wQT;  koff = 128; lstride = 264 * 128; i0 = blk - 384; }
    else if (blk < 1152) { src = msg2_W; dst = w2F;  koff = 0;   lstride = 128 * 128; i0 = blk - 768; }
    else if (blk < 1536) { src = upd1_W; dst = u1aF; koff = 0;   lstride = 261 * 128; i0 = blk - 1152; }
    else if (blk < 1920) { src = upd1_W; dst = u1bF; koff = 128; lstride = 261 * 128; i0 = blk - 1536; }
    else if (blk < 2304) { src = upd2_W; dst = u2F;  koff = 0;   lstride = 128 * 128; i0 = blk - 1920; }
    else if (blk < 2368) { src = emb_W2; dst = eW2F; koff = 0;   lstride = 0; perm = 0; i0 = blk - 2304; }
    else                 { src = out_W1; dst = O1F;  koff = 0;   lstride = 0; ldn = 64; NT = 4; i0 = blk - 2368; }
    int i = i0 * 256 + threadIdx.x;
    int nper = NT << 11;
    int l = i / nper;
    int r0 = i - l * nper;
    int t = r0 >> 11;
    int ks = (r0 >> 9) & 3;
    int lane = (r0 >> 3) & 63;
    int j = r0 & 7;
    int lm = lane & 15, lq = lane >> 4;
    int p = ks * 32 + lq * 8 + j;
    int k = perm ? ((p & 7) * 16 + (p >> 3)) : p;
    int n = t * 16 + lm;
    dst[i] = f2b(src[(size_t)l * lstride + (size_t)(koff + k) * ldn + n]);
}

// ---------- build normalized-f A fragments in registers (f stored bf16 p-space) ----------
__device__ __forceinline__ void build_normf_frags(
    const unsigned short* __restrict__ fB, const float* __restrict__ mr,
    int block0, int b, int w, int lm, int lq, short8* afr)
{
    int row = block0 + w * 16 + lm;
#pragma unroll
    for (int ks = 0; ks < 4; ks++) {
        int po = ks * 32 + lq * 8;
        S8U v; v.s = *(const short8*)(fB + (size_t)row * 128 + po);
        float4 m0 = *(const float4*)(mr + b * 256 + po);
        float4 m1 = *(const float4*)(mr + b * 256 + po + 4);
        float4 s0 = *(const float4*)(mr + b * 256 + 128 + po);
        float4 s1 = *(const float4*)(mr + b * 256 + 128 + po + 4);
        S8U o;
        o.u[0] = pk2((asf(v.u[0] << 16) - m0.x) * s0.x,
                     (asf(v.u[0] & 0xffff0000u) - m0.y) * s0.y);
        o.u[1] = pk2((asf(v.u[1] << 16) - m0.z) * s0.z,
                     (asf(v.u[1] & 0xffff0000u) - m0.w) * s0.w);
        o.u[2] = pk2((asf(v.u[2] << 16) - m1.x) * s1.x,
                     (asf(v.u[2] & 0xffff0000u) - m1.y) * s1.y);
        o.u[3] = pk2((asf(v.u[3] << 16) - m1.z) * s1.z,
                     (asf(v.u[3] & 0xffff0000u) - m1.w) * s1.w);
        afr[ks] = o.s;
    }
}

// ---------- embedding (+ node scalars + mr/cnt init): 8 -> 128 -> 128 ----------
__global__ __launch_bounds__(256) void embed_mfma(
    const float* __restrict__ inp, const float* __restrict__ cp,
    const float* __restrict__ W1, const float* __restrict__ b1,
    const unsigned short* __restrict__ W2F, const float* __restrict__ b2,
    unsigned short* __restrict__ fB, float* __restrict__ u,
    float* __restrict__ posx, float* __restrict__ posy, float* __restrict__ mr,
    int* __restrict__ cnt)
{
    __shared__ unsigned short lA[4 * 272 * 8];
    __shared__ unsigned short lB[1024 * 8];
    int tid = threadIdx.x;
    int block0 = blockIdx.x * 64;
    if (blockIdx.x < 4) mr[blockIdx.x * 256 + tid] = ((tid >> 7) & 1) ? 1.f : 0.f;
    if (blockIdx.x == 4 && tid < 24) cnt[tid] = 0;
    {
        int r = tid >> 2, p4 = tid & 3;
        int n = block0 + r;
        int b = n >> 14;
        int rr = n & 16383;
        int aa = rr >> 7, cc = rr & 127;
        float uu = inp[b * 3 * NBAT + rr];
        float pxx = (aa * (1.f / 127.f)) * cp[b * NP + 1];
        float pyy = (cc * (1.f / 127.f)) * cp[b * NP + 0];
        if (p4 == 0) { u[n] = uu; posx[n] = pxx; posy[n] = pyy; }
        float e8[8];
        e8[0] = uu; e8[1] = pxx; e8[2] = pyy;
#pragma unroll
        for (int p = 0; p < 5; p++) e8[3 + p] = cp[b * NP + p];
        float a32[32];
        const float4* b4 = (const float4*)(b1 + p4 * 32);
#pragma unroll
        for (int q = 0; q < 8; q++) {
            float4 bv = b4[q];
            a32[q * 4 + 0] = bv.x; a32[q * 4 + 1] = bv.y;
            a32[q * 4 + 2] = bv.z; a32[q * 4 + 3] = bv.w;
        }
#pragma unroll
        for (int i = 0; i < 8; i++) {
            const float4* w4 = (const float4*)(W1 + i * 128 + p4 * 32);
            float ev = e8[i];
#pragma unroll
            for (int q = 0; q < 8; q++) {
                float4 wv = w4[q];
                a32[q * 4 + 0] += ev * wv.x; a32[q * 4 + 1] += ev * wv.y;
                a32[q * 4 + 2] += ev * wv.z; a32[q * 4 + 3] += ev * wv.w;
            }
        }
#pragma unroll
        for (int j = 0; j < 4; j++) {
            S8U o;
#pragma unroll
            for (int q = 0; q < 4; q++)
                o.u[q] = pk2(swishf(a32[j * 8 + 2 * q]), swishf(a32[j * 8 + 2 * q + 1]));
            *(short8*)(lA + CHP(r >> 4, p4 * 4 + j, r & 15)) = o.s;
        }
    }
    int w = tid >> 6, lane = tid & 63, lm = lane & 15, lq = lane >> 4;
    float bias2[8];
#pragma unroll
    for (int t = 0; t < 8; t++) bias2[t] = b2[t * 16 + lm];
    floatx4 acc[8];
#pragma unroll
    for (int t = 0; t < 8; t++) acc[t] = (floatx4)(bias2[t]);
    for (int th = 0; th < 2; th++) {
        if (th) __syncthreads();
#pragma unroll
        for (int i = 0; i < 4; i++)
            *(short8*)(lB + (tid + i * 256) * 8) =
                *(const short8*)(W2F + (th * 1024 + tid + i * 256) * 8);
        __syncthreads();
#pragma unroll
        for (int ks = 0; ks < 4; ks++) {
            short8 a = *(const short8*)(lA + CHP(w, ks * 4 + lq, lm));
#pragma unroll
            for (int t2 = 0; t2 < 4; t2++) {
                short8 bf = *(const short8*)(lB + ((t2 * 4 + ks) * 64 + lane) * 8);
                acc[th * 4 + t2] = __builtin_amdgcn_mfma_f32_16x16x32_bf16(a, bf, acc[th * 4 + t2], 0, 0, 0);
            }
        }
    }
#pragma unroll
    for (int r = 0; r < 4; r++) {
        int nd = block0 + w * 16 + lq * 4 + r;
        S8U o;
        o.u[0] = pk2(swishf(acc[0][r]), swishf(acc[1][r]));
        o.u[1] = pk2(swishf(acc[2][r]), swishf(acc[3][r]));
        o.u[2] = pk2(swishf(acc[4][r]), swishf(acc[5][r]));
        o.u[3] = pk2(swishf(acc[6][r]), swishf(acc[7][r]));
        *(short8*)(fB + (size_t)nd * 128 + lm * 8) = o.s;
    }
}

// ---------- pqu: A-frags in regs (norm f bf16); P/Q phases; bf16 P/Q out ----------
__global__ __launch_bounds__(256) void pqu_kernel(
    const unsigned short* __restrict__ fB, const float* __restrict__ mr,
    const unsigned short* __restrict__ wPT, const unsigned short* __restrict__ wQT,
    const float* __restrict__ mW, const float* __restrict__ mb,
    const float* __restrict__ u, const float* __restrict__ px,
    const float* __restrict__ py, const float* __restrict__ cp,
    unsigned short* __restrict__ Pn, unsigned short* __restrict__ Qn)
{
    __shared__ unsigned short lB[2048 * 8];
    int tid = threadIdx.x;
    int block0 = blockIdx.x * 64;
    int b = block0 >> 14;
    int w = tid >> 6, lane = tid & 63, lm = lane & 15, lq = lane >> 4;

    short8 afr[4];
    build_normf_frags(fB, mr, block0, b, w, lm, lq, afr);

    float u4[4], px4[4], py4[4];
#pragma unroll
    for (int r = 0; r < 4; r++) {
        int nd = block0 + w * 16 + lq * 4 + r;
        u4[r] = u[nd]; px4[r] = px[nd]; py4[r] = py[nd];
    }
    float cp5[5];
#pragma unroll
    for (int p = 0; p < 5; p++) cp5[p] = cp[b * NP + p];
    float wu[8], wx[8], wy[8], pt[8];
#pragma unroll
    for (int t = 0; t < 8; t++) {
        int c = t * 16 + lm;
        wu[t] = mW[256 * 128 + c]; wx[t] = mW[257 * 128 + c]; wy[t] = mW[258 * 128 + c];
        float p0 = mb[c];
#pragma unroll
        for (int p = 0; p < 5; p++) p0 += cp5[p] * mW[(259 + p) * 128 + c];
        pt[t] = p0;
    }

    for (int ph = 0; ph < 2; ph++) {
        const unsigned short* bsrc = (ph == 0) ? wPT : wQT;
        if (ph) __syncthreads();
#pragma unroll
        for (int i = 0; i < 8; i++)
            *(short8*)(lB + (tid + i * 256) * 8) = *(const short8*)(bsrc + (tid + i * 256) * 8);
        __syncthreads();
        floatx4 acc[8];
#pragma unroll
        for (int t = 0; t < 8; t++) acc[t] = (ph == 0) ? (floatx4)(pt[t]) : (floatx4)(0.f);
#pragma unroll
        for (int ks = 0; ks < 4; ks++) {
#pragma unroll
            for (int t = 0; t < 8; t++) {
                short8 bf = *(const short8*)(lB + ((t * 4 + ks) * 64 + lane) * 8);
                acc[t] = __builtin_amdgcn_mfma_f32_16x16x32_bf16(afr[ks], bf, acc[t], 0, 0, 0);
            }
        }
        if (ph == 0) {
#pragma unroll
            for (int r = 0; r < 4; r++) {
                int nd = block0 + w * 16 + lq * 4 + r;
                float sc0 = u4[r], sc1 = px4[r], sc2 = py4[r];
                float v[8];
#pragma unroll
                for (int t = 0; t < 8; t++)
                    v[t] = acc[t][r] + sc0 * wu[t] + sc1 * wx[t] + sc2 * wy[t];
                S8U o;
#pragma unroll
                for (int q = 0; q < 4; q++) o.u[q] = pk2(v[2 * q], v[2 * q + 1]);
                *(short8*)(Pn + (size_t)nd * 128 + lm * 8) = o.s;
            }
        } else {
#pragma unroll
            for (int r = 0; r < 4; r++) {
                int nd = block0 + w * 16 + lq * 4 + r;
                float sc0 = u4[r], sc1 = px4[r], sc2 = py4[r];
                float v[8];
#pragma unroll
                for (int t = 0; t < 8; t++)
                    v[t] = acc[t][r] - (sc0 * wu[t] + sc1 * wx[t] + sc2 * wy[t]);
                S8U o;
#pragma unroll
                for (int q = 0; q < 4; q++) o.u[q] = pk2(v[2 * q], v[2 * q + 1]);
                *(short8*)(Qn + (size_t)nd * 128 + lm * 8) = o.s;
            }
        }
    }
}

// ---------- msg: bf16 P/Q; bias-in-acc; interior fast path; half-staged W2 ----------
__global__ __launch_bounds__(256) void msg_kernel(
    const unsigned short* __restrict__ Pn, const unsigned short* __restrict__ Qn,
    const unsigned short* __restrict__ w2F, const float* __restrict__ b2,
    unsigned short* __restrict__ aggF)
{
    __shared__ unsigned short lB[1024 * 8];
    __shared__ unsigned short lAgg[8 * 128];
    int tid = threadIdx.x;
    int base = blockIdx.x * 8;
    int b = base >> 14;
    int a = (base >> 7) & 127;
    int c0 = base & 127;
    int w = tid >> 6, lane = tid & 63, lm = lane & 15, lq = lane >> 4;
    bool interior = (a > 0) & (a < 127) & (c0 > 0) & (c0 + 8 < 128);

    // build hidden A-fragments in registers (swish(P[t]+Q[s]))
    short8 afr[4];
    {
        int tl = lm >> 3, e = lm & 7;
        int idx = (e < 4) ? e : e + 1;
        int dx = idx / 3 - 1, dy = idx % 3 - 1;
        int cc = c0 + w * 2 + tl;
        int na = a + dx, nc = cc + dy;
        int t = base + w * 2 + tl;
        int s;
        if (interior) s = (b << 14) + (na << 7) + nc;
        else {
            bool valid = (na >= 0) & (na < 128) & (nc >= 0) & (nc < 128);
            s = valid ? ((b << 14) + (na << 7) + nc) : t;
        }
#pragma unroll
        for (int ks = 0; ks < 4; ks++) {
            int po = ks * 32 + lq * 8;
            S8U pv, qv, o;
            pv.s = *(const short8*)(Pn + (size_t)t * 128 + po);
            qv.s = *(const short8*)(Qn + (size_t)s * 128 + po);
#pragma unroll
            for (int q = 0; q < 4; q++) {
                float pl = asf(pv.u[q] << 16), ph = asf(pv.u[q] & 0xffff0000u);
                float ql = asf(qv.u[q] << 16), qh = asf(qv.u[q] & 0xffff0000u);
                o.u[q] = pk2(swishf(pl + ql), swishf(ph + qh));
            }
            afr[ks] = o.s;
        }
    }

    float b2v[8];
#pragma unroll
    for (int t = 0; t < 8; t++) b2v[t] = b2[t * 16 + lm];
    floatx4 acc[8];
#pragma unroll
    for (int t = 0; t < 8; t++) acc[t] = (floatx4)(b2v[t]);
    for (int th = 0; th < 2; th++) {
        if (th) __syncthreads();
#pragma unroll
        for (int i = 0; i < 4; i++)
            *(short8*)(lB + (tid + i * 256) * 8) =
                *(const short8*)(w2F + (th * 1024 + tid + i * 256) * 8);
        __syncthreads();
#pragma unroll
        for (int ks = 0; ks < 4; ks++) {
#pragma unroll
            for (int t2 = 0; t2 < 4; t2++) {
                short8 bf = *(const short8*)(lB + ((t2 * 4 + ks) * 64 + lane) * 8);
                acc[th * 4 + t2] = __builtin_amdgcn_mfma_f32_16x16x32_bf16(afr[ks], bf, acc[th * 4 + t2], 0, 0, 0);
            }
        }
    }

    // epilogue
    if (interior) {
        float ov[8];
#pragma unroll
        for (int t = 0; t < 8; t++) {
            float s01 = swishf(acc[t][0]) + swishf(acc[t][1])
                      + swishf(acc[t][2]) + swishf(acc[t][3]);
            ov[t] = s01 + __shfl_xor(s01, 16);
        }
        if ((lq & 1) == 0) {
            int tl = w * 2 + (lq >> 1);
            S8U o;
#pragma unroll
            for (int q = 0; q < 4; q++)
                o.u[q] = pk2(ov[2 * q] * 0.125f, ov[2 * q + 1] * 0.125f);
            *(short8*)(lAgg + tl * 128 + lm * 8) = o.s;
        }
    } else {
        bool vr[4];
#pragma unroll
        for (int r = 0; r < 4; r++) {
            int row16 = lq * 4 + r;
            int tl2 = row16 >> 3, e = row16 & 7;
            int idx = (e < 4) ? e : e + 1;
            int dx = idx / 3 - 1, dy = idx % 3 - 1;
            int cc = c0 + w * 2 + tl2;
            int na = a + dx, nc = cc + dy;
            vr[r] = (na >= 0) & (na < 128) & (nc >= 0) & (nc < 128);
        }
        float ov[8];
#pragma unroll
        for (int t = 0; t < 8; t++) {
            float s01 = 0.f;
#pragma unroll
            for (int r = 0; r < 4; r++)
                s01 += vr[r] ? swishf(acc[t][r]) : 0.f;
            ov[t] = s01 + __shfl_xor(s01, 16);
        }
        if ((lq & 1) == 0) {
            int tl = w * 2 + (lq >> 1);
            int cc = c0 + tl;
            int deg = (1 + (a > 0) + (a < 127)) * (1 + (cc > 0) + (cc < 127)) - 1;
            float inv = 1.f / (float)deg;
            S8U o;
#pragma unroll
            for (int q = 0; q < 4; q++) o.u[q] = pk2(ov[2 * q] * inv, ov[2 * q + 1] * inv);
            *(short8*)(lAgg + tl * 128 + lm * 8) = o.s;
        }
    }
    __syncthreads();
    if (tid < 128) {
        int row8 = tid >> 4, g = tid & 15;
        int n = base + row8;
        size_t lin = (size_t)(n >> 6) * 1024 + (size_t)(((n & 63) >> 4) * 256 + g * 16 + (n & 15));
        *(short8*)(aggF + lin * 8) = *(const short8*)(lAgg + row8 * 128 + g * 8);
    }
}

// ---------- updf: biases in acc; half-staged B; bf16 f; fused per-batch finalize ----------
__global__ __launch_bounds__(256) void updf_kernel(
    unsigned short* __restrict__ fB, float* __restrict__ mr,
    const unsigned short* __restrict__ aggF,
    const unsigned short* __restrict__ u1aF, const unsigned short* __restrict__ u1bF,
    const unsigned short* __restrict__ u2F,
    const float* __restrict__ U1, const float* __restrict__ c1,
    const float* __restrict__ c2, const float* __restrict__ cp,
    float* __restrict__ partials, int* __restrict__ cnt)
{
    __shared__ unsigned short lA[4 * 272 * 8];   // hid (padded); later reduce buffer
    __shared__ unsigned short lB[1024 * 8];
    __shared__ bool isLast;
    int tid = threadIdx.x;
    int block0 = blockIdx.x * 64;
    int b = block0 >> 14;
    int w = tid >> 6, lane = tid & 63, lm = lane & 15, lq = lane >> 4;

    float cp5[5];
#pragma unroll
    for (int p = 0; p < 5; p++) cp5[p] = cp[b * NP + p];
    float pt[8];
#pragma unroll
    for (int t = 0; t < 8; t++) {
        int c = t * 16 + lm;
        float p0 = c1[c];
#pragma unroll
        for (int p = 0; p < 5; p++) p0 += cp5[p] * U1[(256 + p) * 128 + c];
        pt[t] = p0;
    }

    short8 afr[4];
    build_normf_frags(fB, mr, block0, b, w, lm, lq, afr);
    floatx4 acc[8];
#pragma unroll
    for (int t = 0; t < 8; t++) acc[t] = (floatx4)(pt[t]);

    // phases 1 & 2: acc += normf @ U1a + agg @ U1b
    for (int ph = 0; ph < 2; ph++) {
        const unsigned short* bsrc = ph ? u1bF : u1aF;
        if (ph) {
#pragma unroll
            for (int ks = 0; ks < 4; ks++)
                afr[ks] = *(const short8*)(aggF +
                    ((size_t)blockIdx.x * 1024 + w * 256 + (ks * 4 + lq) * 16 + lm) * 8);
        }
        for (int th = 0; th < 2; th++) {
            if (ph | th) __syncthreads();
#pragma unroll
            for (int i = 0; i < 4; i++)
                *(short8*)(lB + (tid + i * 256) * 8) =
                    *(const short8*)(bsrc + (th * 1024 + tid + i * 256) * 8);
            __syncthreads();
#pragma unroll
            for (int ks = 0; ks < 4; ks++) {
#pragma unroll
                for (int t2 = 0; t2 < 4; t2++) {
                    short8 bf = *(const short8*)(lB + ((t2 * 4 + ks) * 64 + lane) * 8);
                    acc[th * 4 + t2] = __builtin_amdgcn_mfma_f32_16x16x32_bf16(afr[ks], bf, acc[th * 4 + t2], 0, 0, 0);
                }
            }
        }
    }

    // epi1: h = swish(acc) -> lA (padded)
#pragma unroll
    for (int r = 0; r < 4; r++) {
        S8U o;
#pragma unroll
        for (int q = 0; q < 4; q++)
            o.u[q] = pk2(swishf(acc[2 * q][r]), swishf(acc[2 * q + 1][r]));
        *(short8*)(lA + CHP(w, lm, lq * 4 + r)) = o.s;
    }

    // phase 3: acc = c2 + hid @ U2
    float c2v[8];
#pragma unroll
    for (int t = 0; t < 8; t++) c2v[t] = c2[t * 16 + lm];
#pragma unroll
    for (int t = 0; t < 8; t++) acc[t] = (floatx4)(c2v[t]);
    for (int th = 0; th < 2; th++) {
        __syncthreads();
#pragma unroll
        for (int i = 0; i < 4; i++)
            *(short8*)(lB + (tid + i * 256) * 8) =
                *(const short8*)(u2F + (th * 1024 + tid + i * 256) * 8);
        __syncthreads();
#pragma unroll
        for (int ks = 0; ks < 4; ks++) {
            short8 a = *(const short8*)(lA + CHP(w, ks * 4 + lq, lm));
#pragma unroll
            for (int t2 = 0; t2 < 4; t2++) {
                short8 bf = *(const short8*)(lB + ((t2 * 4 + ks) * 64 + lane) * 8);
                acc[th * 4 + t2] = __builtin_amdgcn_mfma_f32_16x16x32_bf16(a, bf, acc[th * 4 + t2], 0, 0, 0);
            }
        }
    }

    // epi2: fn = norm(f_old) + swish(acc); write f (bf16); partial stats
    float4 me0 = *(const float4*)(mr + b * 256 + lm * 8);
    float4 me1 = *(const float4*)(mr + b * 256 + lm * 8 + 4);
    float4 rs0 = *(const float4*)(mr + b * 256 + 128 + lm * 8);
    float4 rs1 = *(const float4*)(mr + b * 256 + 128 + lm * 8 + 4);
    float ssum[8], ssq[8];
#pragma unroll
    for (int t = 0; t < 8; t++) { ssum[t] = 0.f; ssq[t] = 0.f; }
#pragma unroll
    for (int r = 0; r < 4; r++) {
        int nd = block0 + w * 16 + lq * 4 + r;
        S8U fo; fo.s = *(const short8*)(fB + (size_t)nd * 128 + lm * 8);
        float fn[8];
        fn[0] = (asf(fo.u[0] << 16)        - me0.x) * rs0.x + swishf(acc[0][r]);
        fn[1] = (asf(fo.u[0] & 0xffff0000u) - me0.y) * rs0.y + swishf(acc[1][r]);
        fn[2] = (asf(fo.u[1] << 16)        - me0.z) * rs0.z + swishf(acc[2][r]);
        fn[3] = (asf(fo.u[1] & 0xffff0000u) - me0.w) * rs0.w + swishf(acc[3][r]);
        fn[4] = (asf(fo.u[2] << 16)        - me1.x) * rs1.x + swishf(acc[4][r]);
        fn[5] = (asf(fo.u[2] & 0xffff0000u) - me1.y) * rs1.y + swishf(acc[5][r]);
        fn[6] = (asf(fo.u[3] << 16)        - me1.z) * rs1.z + swishf(acc[6][r]);
        fn[7] = (asf(fo.u[3] & 0xffff0000u) - me1.w) * rs1.w + swishf(acc[7][r]);
        S8U o;
        o.u[0] = pk2(fn[0], fn[1]); o.u[1] = pk2(fn[2], fn[3]);
        o.u[2] = pk2(fn[4], fn[5]); o.u[3] = pk2(fn[6], fn[7]);
        *(short8*)(fB + (size_t)nd * 128 + lm * 8) = o.s;
#pragma unroll
        for (int t = 0; t < 8; t++) { ssum[t] += fn[t]; ssq[t] += fn[t] * fn[t]; }
    }
#pragma unroll
    for (int t = 0; t < 8; t++) {
        ssum[t] += __shfl_xor(ssum[t], 16); ssum[t] += __shfl_xor(ssum[t], 32);
        ssq[t]  += __shfl_xor(ssq[t], 16);  ssq[t]  += __shfl_xor(ssq[t], 32);
    }
    __syncthreads();
    float* red = (float*)lA;
    if (lq == 0) {
#pragma unroll
        for (int t = 0; t < 8; t++) {
            red[w * 256 + lm * 8 + t] = ssum[t];
            red[w * 256 + 128 + lm * 8 + t] = ssq[t];
        }
    }
    __syncthreads();
    {
        float v = red[tid] + red[256 + tid] + red[512 + tid] + red[768 + tid];
        partials[(size_t)blockIdx.x * 256 + tid] = v;
    }
    // fused finalize: last block of each batch reduces its 256 partial rows -> mr
    __threadfence();
    __syncthreads();
    if (tid == 0) isLast = (atomicAdd(&cnt[b], 1) == 255);
    __syncthreads();
    if (isLast) {
        __threadfence();
        float acc2 = 0.f;
        const float* pp = partials + (size_t)b * 65536 + tid;
#pragma unroll 8
        for (int i = 0; i < 256; i++) acc2 += pp[i * 256];
        red[tid] = acc2;
        __syncthreads();
        if (tid < 128) {
            float mean = red[tid] * (1.f / 16384.f);
            float var = red[128 + tid] * (1.f / 16384.f) - mean * mean;
            mr[b * 256 + tid] = mean;
            mr[b * 256 + 128 + tid] = rsqrtf(var + EPS);
        }
    }
}

// ---------- output head ----------
__global__ __launch_bounds__(256) void out_head(
    const unsigned short* __restrict__ fB, const float* __restrict__ mr,
    const unsigned short* __restrict__ O1F, const float* __restrict__ ob1,
    const float* __restrict__ O2, const float* __restrict__ ob2,
    const float* __restrict__ u, float* __restrict__ out)
{
    __shared__ unsigned short lB[1024 * 8];
    int tid = threadIdx.x;
    int block0 = blockIdx.x * 64;
    int b = block0 >> 14;
    int w = tid >> 6, lane = tid & 63, lm = lane & 15, lq = lane >> 4;
#pragma unroll
    for (int i = 0; i < 4; i++)
        *(short8*)(lB + (tid + i * 256) * 8) = *(const short8*)(O1F + (tid + i * 256) * 8);
    short8 afr[4];
    build_normf_frags(fB, mr, block0, b, w, lm, lq, afr);
    float b1v[4], o2v[4];
#pragma unroll
    for (int t = 0; t < 4; t++) {
        b1v[t] = ob1[t * 16 + lm];
        o2v[t] = O2[t * 16 + lm];
    }
    __syncthreads();
    floatx4 acc[4];
#pragma unroll
    for (int t = 0; t < 4; t++) acc[t] = (floatx4)(b1v[t]);
#pragma unroll
    for (int ks = 0; ks < 4; ks++) {
#pragma unroll
        for (int t = 0; t < 4; t++) {
            short8 bf = *(const short8*)(lB + ((t * 4 + ks) * 64 + lane) * 8);
            acc[t] = __builtin_amdgcn_mfma_f32_16x16x32_bf16(afr[ks], bf, acc[t], 0, 0, 0);
        }
    }
    float ob2v = ob2[0];
#pragma unroll
    for (int r = 0; r < 4; r++) {
        float s = 0.f;
#pragma unroll
        for (int t = 0; t < 4; t++) s += swishf(acc[t][r]) * o2v[t];
        s += __shfl_xor(s, 1); s += __shfl_xor(s, 2);
        s += __shfl_xor(s, 4); s += __shfl_xor(s, 8);
        if (lm == 0) {
            int nd = block0 + w * 16 + lq * 4 + r;
            out[nd] = u[nd] + DT * (s + ob2v);
        }
    }
}

extern "C" void kernel_launch(void* const* d_in, const int* in_sizes, int n_in,
                              void* d_out, int out_size, void* d_ws, size_t ws_size,
                              hipStream_t stream)
{
    const float* inputs = (const float*)d_in[0];
    const float* cp     = (const float*)d_in[1];
    const float* emb_W1 = (const float*)d_in[3];
    const float* emb_b1 = (const float*)d_in[4];
    const float* emb_W2 = (const float*)d_in[5];
    const float* emb_b2 = (const float*)d_in[6];
    const float* msg1_W = (const float*)d_in[7];
    const float* msg1_b = (const float*)d_in[8];
    const float* msg2_W = (const float*)d_in[9];
    const float* msg2_b = (const float*)d_in[10];
    const float* upd1_W = (const float*)d_in[11];
    const float* upd1_b = (const float*)d_in[12];
    const float* upd2_W = (const float*)d_in[13];
    const float* upd2_b = (const float*)d_in[14];
    const float* out_W1 = (const float*)d_in[15];
    const float* out_b1 = (const float*)d_in[16];
    const float* out_W2 = (const float*)d_in[17];
    const float* out_b2 = (const float*)d_in[18];
    float* out = (float*)d_out;

    char* base = (char*)d_ws;
    size_t off = 0;
    unsigned short* fB   = (unsigned short*)(base + off); off += (size_t)NNODE * 128 * 2;
    unsigned short* Pn   = (unsigned short*)(base + off); off += (size_t)NNODE * 128 * 2;
    unsigned short* Qn   = (unsigned short*)(base + off); off += (size_t)NNODE * 128 * 2;
    unsigned short* aggF = (unsigned short*)(base + off); off += (size_t)NNODE * 128 * 2;
    float* u    = (float*)(base + off); off += NNODE * 4;
    float* posx = (float*)(base + off); off += NNODE * 4;
    float* posy = (float*)(base + off); off += NNODE * 4;
    float* partials = (float*)(base + off); off += 1024 * 256 * 4;
    float* mrbuf = (float*)(base + off); off += 1024 * 4;
    int* cnt = (int*)(base + off); off += 64 * 4;
    unsigned short* wPT  = (unsigned short*)(base + off); off += 6 * 16384 * 2;
    unsigned short* wQT  = (unsigned short*)(base + off); off += 6 * 16384 * 2;
    unsigned short* w2F  = (unsigned short*)(base + off); off += 6 * 16384 * 2;
    unsigned short* u1aF = (unsigned short*)(base + off); off += 6 * 16384 * 2;
    unsigned short* u1bF = (unsigned short*)(base + off); off += 6 * 16384 * 2;
    unsigned short* u2F  = (unsigned short*)(base + off); off += 6 * 16384 * 2;
    unsigned short* eW2F = (unsigned short*)(base + off); off += 16384 * 2;
    unsigned short* O1F  = (unsigned short*)(base + off); off += 8192 * 2;

    prep_all<<<2400, 256, 0, stream>>>(msg1_W, msg2_W, upd1_W, upd2_W, emb_W2, out_W1,
                                       wPT, wQT, w2F, u1aF, u1bF, u2F, eW2F, O1F);
    embed_mfma<<<1024, 256, 0, stream>>>(inputs, cp, emb_W1, emb_b1, eW2F, emb_b2,
                                         fB, u, posx, posy, mrbuf, cnt);
    for (int l = 0; l < 6; l++) {
        pqu_kernel<<<1024, 256, 0, stream>>>(fB, mrbuf,
            wPT + (size_t)l * 16384, wQT + (size_t)l * 16384,
            msg1_W + (size_t)l * 264 * 128, msg1_b + (size_t)l * 128,
            u, posx, posy, cp, Pn, Qn);
        msg_kernel<<<8192, 256, 0, stream>>>(Pn, Qn,
            w2F + (size_t)l * 16384, msg2_b + (size_t)l * 128, aggF);
        updf_kernel<<<1024, 256, 0, stream>>>(fB, mrbuf, aggF,
            u1aF + (size_t)l * 16384, u1bF + (size_t)l * 16384, u2F + (size_t)l * 16384,
            upd1_W + (size_t)l * 261 * 128, upd1_b + (size_t)l * 128,
            upd2_b + (size_t)l * 128, cp, partials, cnt + l * 4);
    }
    out_head<<<1024, 256, 0, stream>>>(fB, mrbuf, O1F, out_b1, out_W2, out_b2, u, out);
}

// Round 11
// 710.934 us; speedup vs baseline: 1.8222x; 1.8222x over previous
//
#include <hip/hip_runtime.h>
#include <hip/hip_bf16.h>
#include <math.h>

#define NNODE 65536
#define NBAT  16384
#define NP    5
#define DT    0.1f
#define EPS   1e-5f

typedef __attribute__((ext_vector_type(8))) short short8;
typedef __attribute__((ext_vector_type(4))) float floatx4;

union S8U { short8 s; unsigned int u[4]; };

// fast swish: x * rcp(1+e^-x)
__device__ __forceinline__ float swishf(float x) {
    return x * __builtin_amdgcn_rcpf(1.f + __expf(-x));
}
__device__ __forceinline__ float asf(unsigned int u) {
    union { unsigned int u; float f; } x; x.u = u; return x.f;
}
__device__ __forceinline__ unsigned short f2b(float f) {
    union { float f; unsigned int u; } x; x.f = f;
    unsigned int r = x.u + 0x7fff + ((x.u >> 16) & 1);
    return (unsigned short)(r >> 16);
}
__device__ __forceinline__ unsigned int pk2(float a, float b) {
    __hip_bfloat162 h = __float22bfloat162_rn(make_float2(a, b));
    union { __hip_bfloat162 h; unsigned int u; } x; x.h = h; return x.u;
}

// padded fragment chunk offset (in shorts)
#define CHP(w, g, r15) ((((w) * 272) + (g) * 17 + (r15)) * 8)

// ---------- fused weight prep: all matrices in one launch ----------
__global__ __launch_bounds__(256) void prep_all(
    const float* __restrict__ msg1_W, const float* __restrict__ msg2_W,
    const float* __restrict__ upd1_W, const float* __restrict__ upd2_W,
    const float* __restrict__ emb_W2, const float* __restrict__ out_W1,
    unsigned short* __restrict__ wPT, unsigned short* __restrict__ wQT,
    unsigned short* __restrict__ w2F, unsigned short* __restrict__ u1aF,
    unsigned short* __restrict__ u1bF, unsigned short* __restrict__ u2F,
    unsigned short* __restrict__ eW2F, unsigned short* __restrict__ O1F)
{
    int blk = blockIdx.x;
    const float* src; unsigned short* dst;
    int ldn = 128, koff, NT = 8, lstride, perm = 1, i0;
    if (blk < 384)       { src = msg1_W; dst = wPT;  koff = 0;   lstride = 264 * 128; i0 = blk; }
    else if (blk < 768)  { src = msg1_W; dst = wQT;  koff = 128; lstride = 264 * 128; i0 = blk - 384; }
    else if (blk < 1152) { src = msg2_W; dst = w2F;  koff = 0;   lstride = 128 * 128; i0 = blk - 768; }
    else if (blk < 1536) { src = upd1_W; dst = u1aF; koff = 0;   lstride = 261 * 128; i0 = blk - 1152; }
    else if (blk < 1920) { src = upd1_W; dst = u1bF; koff = 128; lstride = 261 * 128; i0 = blk - 1536; }
    else if (blk < 2304) { src = upd2_W; dst = u2F;  koff = 0;   lstride = 128 * 128; i0 = blk - 1920; }
    else if (blk < 2368) { src = emb_W2; dst = eW2F; koff = 0;   lstride = 0; perm = 0; i0 = blk - 2304; }
    else                 { src = out_W1; dst = O1F;  koff = 0;   lstride = 0; ldn = 64; NT = 4; i0 = blk - 2368; }
    int i = i0 * 256 + threadIdx.x;
    int nper = NT << 11;
    int l = i / nper;
    int r0 = i - l * nper;
    int t = r0 >> 11;
    int ks = (r0 >> 9) & 3;
    int lane = (r0 >> 3) & 63;
    int j = r0 & 7;
    int lm = lane & 15, lq = lane >> 4;
    int p = ks * 32 + lq * 8 + j;
    int k = perm ? ((p & 7) * 16 + (p >> 3)) : p;
    int n = t * 16 + lm;
    dst[i] = f2b(src[(size_t)l * lstride + (size_t)(koff + k) * ldn + n]);
}

// ---------- build normalized-f A fragments in registers (f stored bf16 p-space) ----------
__device__ __forceinline__ void build_normf_frags(
    const unsigned short* __restrict__ fB, const float* __restrict__ mr,
    int block0, int b, int w, int lm, int lq, short8* afr)
{
    int row = block0 + w * 16 + lm;
#pragma unroll
    for (int ks = 0; ks < 4; ks++) {
        int po = ks * 32 + lq * 8;
        S8U v; v.s = *(const short8*)(fB + (size_t)row * 128 + po);
        float4 m0 = *(const float4*)(mr + b * 256 + po);
        float4 m1 = *(const float4*)(mr + b * 256 + po + 4);
        float4 s0 = *(const float4*)(mr + b * 256 + 128 + po);
        float4 s1 = *(const float4*)(mr + b * 256 + 128 + po + 4);
        S8U o;
        o.u[0] = pk2((asf(v.u[0] << 16) - m0.x) * s0.x,
                     (asf(v.u[0] & 0xffff0000u) - m0.y) * s0.y);
        o.u[1] = pk2((asf(v.u[1] << 16) - m0.z) * s0.z,
                     (asf(v.u[1] & 0xffff0000u) - m0.w) * s0.w);
        o.u[2] = pk2((asf(v.u[2] << 16) - m1.x) * s1.x,
                     (asf(v.u[2] & 0xffff0000u) - m1.y) * s1.y);
        o.u[3] = pk2((asf(v.u[3] << 16) - m1.z) * s1.z,
                     (asf(v.u[3] & 0xffff0000u) - m1.w) * s1.w);
        afr[ks] = o.s;
    }
}

// ---------- embedding (+ node scalars + mr init): 8 -> 128 -> 128 ----------
__global__ __launch_bounds__(256) void embed_mfma(
    const float* __restrict__ inp, const float* __restrict__ cp,
    const float* __restrict__ W1, const float* __restrict__ b1,
    const unsigned short* __restrict__ W2F, const float* __restrict__ b2,
    unsigned short* __restrict__ fB, float* __restrict__ u,
    float* __restrict__ posx, float* __restrict__ posy, float* __restrict__ mr)
{
    __shared__ unsigned short lA[4 * 272 * 8];
    __shared__ unsigned short lB[1024 * 8];
    int tid = threadIdx.x;
    int block0 = blockIdx.x * 64;
    if (blockIdx.x < 4) mr[blockIdx.x * 256 + tid] = ((tid >> 7) & 1) ? 1.f : 0.f;
    {
        int r = tid >> 2, p4 = tid & 3;
        int n = block0 + r;
        int b = n >> 14;
        int rr = n & 16383;
        int aa = rr >> 7, cc = rr & 127;
        float uu = inp[b * 3 * NBAT + rr];
        float pxx = (aa * (1.f / 127.f)) * cp[b * NP + 1];
        float pyy = (cc * (1.f / 127.f)) * cp[b * NP + 0];
        if (p4 == 0) { u[n] = uu; posx[n] = pxx; posy[n] = pyy; }
        float e8[8];
        e8[0] = uu; e8[1] = pxx; e8[2] = pyy;
#pragma unroll
        for (int p = 0; p < 5; p++) e8[3 + p] = cp[b * NP + p];
        float a32[32];
        const float4* b4 = (const float4*)(b1 + p4 * 32);
#pragma unroll
        for (int q = 0; q < 8; q++) {
            float4 bv = b4[q];
            a32[q * 4 + 0] = bv.x; a32[q * 4 + 1] = bv.y;
            a32[q * 4 + 2] = bv.z; a32[q * 4 + 3] = bv.w;
        }
#pragma unroll
        for (int i = 0; i < 8; i++) {
            const float4* w4 = (const float4*)(W1 + i * 128 + p4 * 32);
            float ev = e8[i];
#pragma unroll
            for (int q = 0; q < 8; q++) {
                float4 wv = w4[q];
                a32[q * 4 + 0] += ev * wv.x; a32[q * 4 + 1] += ev * wv.y;
                a32[q * 4 + 2] += ev * wv.z; a32[q * 4 + 3] += ev * wv.w;
            }
        }
#pragma unroll
        for (int j = 0; j < 4; j++) {
            S8U o;
#pragma unroll
            for (int q = 0; q < 4; q++)
                o.u[q] = pk2(swishf(a32[j * 8 + 2 * q]), swishf(a32[j * 8 + 2 * q + 1]));
            *(short8*)(lA + CHP(r >> 4, p4 * 4 + j, r & 15)) = o.s;
        }
    }
    int w = tid >> 6, lane = tid & 63, lm = lane & 15, lq = lane >> 4;
    float bias2[8];
#pragma unroll
    for (int t = 0; t < 8; t++) bias2[t] = b2[t * 16 + lm];
    floatx4 acc[8];
#pragma unroll
    for (int t = 0; t < 8; t++) acc[t] = (floatx4)(bias2[t]);
    for (int th = 0; th < 2; th++) {
        if (th) __syncthreads();
#pragma unroll
        for (int i = 0; i < 4; i++)
            *(short8*)(lB + (tid + i * 256) * 8) =
                *(const short8*)(W2F + (th * 1024 + tid + i * 256) * 8);
        __syncthreads();
#pragma unroll
        for (int ks = 0; ks < 4; ks++) {
            short8 a = *(const short8*)(lA + CHP(w, ks * 4 + lq, lm));
#pragma unroll
            for (int t2 = 0; t2 < 4; t2++) {
                short8 bf = *(const short8*)(lB + ((t2 * 4 + ks) * 64 + lane) * 8);
                acc[th * 4 + t2] = __builtin_amdgcn_mfma_f32_16x16x32_bf16(a, bf, acc[th * 4 + t2], 0, 0, 0);
            }
        }
    }
#pragma unroll
    for (int r = 0; r < 4; r++) {
        int nd = block0 + w * 16 + lq * 4 + r;
        S8U o;
        o.u[0] = pk2(swishf(acc[0][r]), swishf(acc[1][r]));
        o.u[1] = pk2(swishf(acc[2][r]), swishf(acc[3][r]));
        o.u[2] = pk2(swishf(acc[4][r]), swishf(acc[5][r]));
        o.u[3] = pk2(swishf(acc[6][r]), swishf(acc[7][r]));
        *(short8*)(fB + (size_t)nd * 128 + lm * 8) = o.s;
    }
}

// ---------- pqu: A-frags in regs (norm f bf16); P/Q phases; bf16 P/Q out ----------
__global__ __launch_bounds__(256) void pqu_kernel(
    const unsigned short* __restrict__ fB, const float* __restrict__ mr,
    const unsigned short* __restrict__ wPT, const unsigned short* __restrict__ wQT,
    const float* __restrict__ mW, const float* __restrict__ mb,
    const float* __restrict__ u, const float* __restrict__ px,
    const float* __restrict__ py, const float* __restrict__ cp,
    unsigned short* __restrict__ Pn, unsigned short* __restrict__ Qn)
{
    __shared__ unsigned short lB[2048 * 8];
    int tid = threadIdx.x;
    int block0 = blockIdx.x * 64;
    int b = block0 >> 14;
    int w = tid >> 6, lane = tid & 63, lm = lane & 15, lq = lane >> 4;

    short8 afr[4];
    build_normf_frags(fB, mr, block0, b, w, lm, lq, afr);

    float u4[4], px4[4], py4[4];
#pragma unroll
    for (int r = 0; r < 4; r++) {
        int nd = block0 + w * 16 + lq * 4 + r;
        u4[r] = u[nd]; px4[r] = px[nd]; py4[r] = py[nd];
    }
    float cp5[5];
#pragma unroll
    for (int p = 0; p < 5; p++) cp5[p] = cp[b * NP + p];
    float wu[8], wx[8], wy[8], pt[8];
#pragma unroll
    for (int t = 0; t < 8; t++) {
        int c = t * 16 + lm;
        wu[t] = mW[256 * 128 + c]; wx[t] = mW[257 * 128 + c]; wy[t] = mW[258 * 128 + c];
        float p0 = mb[c];
#pragma unroll
        for (int p = 0; p < 5; p++) p0 += cp5[p] * mW[(259 + p) * 128 + c];
        pt[t] = p0;
    }

    for (int ph = 0; ph < 2; ph++) {
        const unsigned short* bsrc = (ph == 0) ? wPT : wQT;
        if (ph) __syncthreads();
#pragma unroll
        for (int i = 0; i < 8; i++)
            *(short8*)(lB + (tid + i * 256) * 8) = *(const short8*)(bsrc + (tid + i * 256) * 8);
        __syncthreads();
        floatx4 acc[8];
#pragma unroll
        for (int t = 0; t < 8; t++) acc[t] = (ph == 0) ? (floatx4)(pt[t]) : (floatx4)(0.f);
#pragma unroll
        for (int ks = 0; ks < 4; ks++) {
#pragma unroll
            for (int t = 0; t < 8; t++) {
                short8 bf = *(const short8*)(lB + ((t * 4 + ks) * 64 + lane) * 8);
                acc[t] = __builtin_amdgcn_mfma_f32_16x16x32_bf16(afr[ks], bf, acc[t], 0, 0, 0);
            }
        }
        if (ph == 0) {
#pragma unroll
            for (int r = 0; r < 4; r++) {
                int nd = block0 + w * 16 + lq * 4 + r;
                float sc0 = u4[r], sc1 = px4[r], sc2 = py4[r];
                float v[8];
#pragma unroll
                for (int t = 0; t < 8; t++)
                    v[t] = acc[t][r] + sc0 * wu[t] + sc1 * wx[t] + sc2 * wy[t];
                S8U o;
#pragma unroll
                for (int q = 0; q < 4; q++) o.u[q] = pk2(v[2 * q], v[2 * q + 1]);
                *(short8*)(Pn + (size_t)nd * 128 + lm * 8) = o.s;
            }
        } else {
#pragma unroll
            for (int r = 0; r < 4; r++) {
                int nd = block0 + w * 16 + lq * 4 + r;
                float sc0 = u4[r], sc1 = px4[r], sc2 = py4[r];
                float v[8];
#pragma unroll
                for (int t = 0; t < 8; t++)
                    v[t] = acc[t][r] - (sc0 * wu[t] + sc1 * wx[t] + sc2 * wy[t]);
                S8U o;
#pragma unroll
                for (int q = 0; q < 4; q++) o.u[q] = pk2(v[2 * q], v[2 * q + 1]);
                *(short8*)(Qn + (size_t)nd * 128 + lm * 8) = o.s;
            }
        }
    }
}

// ---------- msg: bf16 P/Q; bias-in-acc; interior fast path; half-staged W2 ----------
__global__ __launch_bounds__(256) void msg_kernel(
    const unsigned short* __restrict__ Pn, const unsigned short* __restrict__ Qn,
    const unsigned short* __restrict__ w2F, const float* __restrict__ b2,
    unsigned short* __restrict__ aggF)
{
    __shared__ unsigned short lB[1024 * 8];
    __shared__ unsigned short lAgg[8 * 128];
    int tid = threadIdx.x;
    int base = blockIdx.x * 8;
    int b = base >> 14;
    int a = (base >> 7) & 127;
    int c0 = base & 127;
    int w = tid >> 6, lane = tid & 63, lm = lane & 15, lq = lane >> 4;
    bool interior = (a > 0) & (a < 127) & (c0 > 0) & (c0 + 8 < 128);

    // build hidden A-fragments in registers (swish(P[t]+Q[s]))
    short8 afr[4];
    {
        int tl = lm >> 3, e = lm & 7;
        int idx = (e < 4) ? e : e + 1;
        int dx = idx / 3 - 1, dy = idx % 3 - 1;
        int cc = c0 + w * 2 + tl;
        int na = a + dx, nc = cc + dy;
        int t = base + w * 2 + tl;
        int s;
        if (interior) s = (b << 14) + (na << 7) + nc;
        else {
            bool valid = (na >= 0) & (na < 128) & (nc >= 0) & (nc < 128);
            s = valid ? ((b << 14) + (na << 7) + nc) : t;
        }
#pragma unroll
        for (int ks = 0; ks < 4; ks++) {
            int po = ks * 32 + lq * 8;
            S8U pv, qv, o;
            pv.s = *(const short8*)(Pn + (size_t)t * 128 + po);
            qv.s = *(const short8*)(Qn + (size_t)s * 128 + po);
#pragma unroll
            for (int q = 0; q < 4; q++) {
                float pl = asf(pv.u[q] << 16), ph = asf(pv.u[q] & 0xffff0000u);
                float ql = asf(qv.u[q] << 16), qh = asf(qv.u[q] & 0xffff0000u);
                o.u[q] = pk2(swishf(pl + ql), swishf(ph + qh));
            }
            afr[ks] = o.s;
        }
    }

    float b2v[8];
#pragma unroll
    for (int t = 0; t < 8; t++) b2v[t] = b2[t * 16 + lm];
    floatx4 acc[8];
#pragma unroll
    for (int t = 0; t < 8; t++) acc[t] = (floatx4)(b2v[t]);
    for (int th = 0; th < 2; th++) {
        if (th) __syncthreads();
#pragma unroll
        for (int i = 0; i < 4; i++)
            *(short8*)(lB + (tid + i * 256) * 8) =
                *(const short8*)(w2F + (th * 1024 + tid + i * 256) * 8);
        __syncthreads();
#pragma unroll
        for (int ks = 0; ks < 4; ks++) {
#pragma unroll
            for (int t2 = 0; t2 < 4; t2++) {
                short8 bf = *(const short8*)(lB + ((t2 * 4 + ks) * 64 + lane) * 8);
                acc[th * 4 + t2] = __builtin_amdgcn_mfma_f32_16x16x32_bf16(afr[ks], bf, acc[th * 4 + t2], 0, 0, 0);
            }
        }
    }

    // epilogue
    if (interior) {
        float ov[8];
#pragma unroll
        for (int t = 0; t < 8; t++) {
            float s01 = swishf(acc[t][0]) + swishf(acc[t][1])
                      + swishf(acc[t][2]) + swishf(acc[t][3]);
            ov[t] = s01 + __shfl_xor(s01, 16);
        }
        if ((lq & 1) == 0) {
            int tl = w * 2 + (lq >> 1);
            S8U o;
#pragma unroll
            for (int q = 0; q < 4; q++)
                o.u[q] = pk2(ov[2 * q] * 0.125f, ov[2 * q + 1] * 0.125f);
            *(short8*)(lAgg + tl * 128 + lm * 8) = o.s;
        }
    } else {
        bool vr[4];
#pragma unroll
        for (int r = 0; r < 4; r++) {
            int row16 = lq * 4 + r;
            int tl2 = row16 >> 3, e = row16 & 7;
            int idx = (e < 4) ? e : e + 1;
            int dx = idx / 3 - 1, dy = idx % 3 - 1;
            int cc = c0 + w * 2 + tl2;
            int na = a + dx, nc = cc + dy;
            vr[r] = (na >= 0) & (na < 128) & (nc >= 0) & (nc < 128);
        }
        float ov[8];
#pragma unroll
        for (int t = 0; t < 8; t++) {
            float s01 = 0.f;
#pragma unroll
            for (int r = 0; r < 4; r++)
                s01 += vr[r] ? swishf(acc[t][r]) : 0.f;
            ov[t] = s01 + __shfl_xor(s01, 16);
        }
        if ((lq & 1) == 0) {
            int tl = w * 2 + (lq >> 1);
            int cc = c0 + tl;
            int deg = (1 + (a > 0) + (a < 127)) * (1 + (cc > 0) + (cc < 127)) - 1;
            float inv = 1.f / (float)deg;
            S8U o;
#pragma unroll
            for (int q = 0; q < 4; q++) o.u[q] = pk2(ov[2 * q] * inv, ov[2 * q + 1] * inv);
            *(short8*)(lAgg + tl * 128 + lm * 8) = o.s;
        }
    }
    __syncthreads();
    if (tid < 128) {
        int row8 = tid >> 4, g = tid & 15;
        int n = base + row8;
        size_t lin = (size_t)(n >> 6) * 1024 + (size_t)(((n & 63) >> 4) * 256 + g * 16 + (n & 15));
        *(short8*)(aggF + lin * 8) = *(const short8*)(lAgg + row8 * 128 + g * 8);
    }
}

// ---------- updf: biases in acc; half-staged B; bf16 f; per-block partials ----------
__global__ __launch_bounds__(256) void updf_kernel(
    unsigned short* __restrict__ fB, const float* __restrict__ mr,
    const unsigned short* __restrict__ aggF,
    const unsigned short* __restrict__ u1aF, const unsigned short* __restrict__ u1bF,
    const unsigned short* __restrict__ u2F,
    const float* __restrict__ U1, const float* __restrict__ c1,
    const float* __restrict__ c2, const float* __restrict__ cp,
    float* __restrict__ partials)
{
    __shared__ unsigned short lA[4 * 272 * 8];   // hid (padded); later reduce buffer
    __shared__ unsigned short lB[1024 * 8];
    int tid = threadIdx.x;
    int block0 = blockIdx.x * 64;
    int b = block0 >> 14;
    int w = tid >> 6, lane = tid & 63, lm = lane & 15, lq = lane >> 4;

    float cp5[5];
#pragma unroll
    for (int p = 0; p < 5; p++) cp5[p] = cp[b * NP + p];
    float pt[8];
#pragma unroll
    for (int t = 0; t < 8; t++) {
        int c = t * 16 + lm;
        float p0 = c1[c];
#pragma unroll
        for (int p = 0; p < 5; p++) p0 += cp5[p] * U1[(256 + p) * 128 + c];
        pt[t] = p0;
    }

    short8 afr[4];
    build_normf_frags(fB, mr, block0, b, w, lm, lq, afr);
    floatx4 acc[8];
#pragma unroll
    for (int t = 0; t < 8; t++) acc[t] = (floatx4)(pt[t]);

    // phases 1 & 2: acc += normf @ U1a + agg @ U1b
    for (int ph = 0; ph < 2; ph++) {
        const unsigned short* bsrc = ph ? u1bF : u1aF;
        if (ph) {
#pragma unroll
            for (int ks = 0; ks < 4; ks++)
                afr[ks] = *(const short8*)(aggF +
                    ((size_t)blockIdx.x * 1024 + w * 256 + (ks * 4 + lq) * 16 + lm) * 8);
        }
        for (int th = 0; th < 2; th++) {
            if (ph | th) __syncthreads();
#pragma unroll
            for (int i = 0; i < 4; i++)
                *(short8*)(lB + (tid + i * 256) * 8) =
                    *(const short8*)(bsrc + (th * 1024 + tid + i * 256) * 8);
            __syncthreads();
#pragma unroll
            for (int ks = 0; ks < 4; ks++) {
#pragma unroll
                for (int t2 = 0; t2 < 4; t2++) {
                    short8 bf = *(const short8*)(lB + ((t2 * 4 + ks) * 64 + lane) * 8);
                    acc[th * 4 + t2] = __builtin_amdgcn_mfma_f32_16x16x32_bf16(afr[ks], bf, acc[th * 4 + t2], 0, 0, 0);
                }
            }
        }
    }

    // epi1: h = swish(acc) -> lA (padded)
#pragma unroll
    for (int r = 0; r < 4; r++) {
        S8U o;
#pragma unroll
        for (int q = 0; q < 4; q++)
            o.u[q] = pk2(swishf(acc[2 * q][r]), swishf(acc[2 * q + 1][r]));
        *(short8*)(lA + CHP(w, lm, lq * 4 + r)) = o.s;
    }

    // phase 3: acc = c2 + hid @ U2
    float c2v[8];
#pragma unroll
    for (int t = 0; t < 8; t++) c2v[t] = c2[t * 16 + lm];
#pragma unroll
    for (int t = 0; t < 8; t++) acc[t] = (floatx4)(c2v[t]);
    for (int th = 0; th < 2; th++) {
        __syncthreads();
#pragma unroll
        for (int i = 0; i < 4; i++)
            *(short8*)(lB + (tid + i * 256) * 8) =
                *(const short8*)(u2F + (th * 1024 + tid + i * 256) * 8);
        __syncthreads();
#pragma unroll
        for (int ks = 0; ks < 4; ks++) {
            short8 a = *(const short8*)(lA + CHP(w, ks * 4 + lq, lm));
#pragma unroll
            for (int t2 = 0; t2 < 4; t2++) {
                short8 bf = *(const short8*)(lB + ((t2 * 4 + ks) * 64 + lane) * 8);
                acc[th * 4 + t2] = __builtin_amdgcn_mfma_f32_16x16x32_bf16(a, bf, acc[th * 4 + t2], 0, 0, 0);
            }
        }
    }

    // epi2: fn = norm(f_old) + swish(acc); write f (bf16); partial stats
    float4 me0 = *(const float4*)(mr + b * 256 + lm * 8);
    float4 me1 = *(const float4*)(mr + b * 256 + lm * 8 + 4);
    float4 rs0 = *(const float4*)(mr + b * 256 + 128 + lm * 8);
    float4 rs1 = *(const float4*)(mr + b * 256 + 128 + lm * 8 + 4);
    float ssum[8], ssq[8];
#pragma unroll
    for (int t = 0; t < 8; t++) { ssum[t] = 0.f; ssq[t] = 0.f; }
#pragma unroll
    for (int r = 0; r < 4; r++) {
        int nd = block0 + w * 16 + lq * 4 + r;
        S8U fo; fo.s = *(const short8*)(fB + (size_t)nd * 128 + lm * 8);
        float fn[8];
        fn[0] = (asf(fo.u[0] << 16)        - me0.x) * rs0.x + swishf(acc[0][r]);
        fn[1] = (asf(fo.u[0] & 0xffff0000u) - me0.y) * rs0.y + swishf(acc[1][r]);
        fn[2] = (asf(fo.u[1] << 16)        - me0.z) * rs0.z + swishf(acc[2][r]);
        fn[3] = (asf(fo.u[1] & 0xffff0000u) - me0.w) * rs0.w + swishf(acc[3][r]);
        fn[4] = (asf(fo.u[2] << 16)        - me1.x) * rs1.x + swishf(acc[4][r]);
        fn[5] = (asf(fo.u[2] & 0xffff0000u) - me1.y) * rs1.y + swishf(acc[5][r]);
        fn[6] = (asf(fo.u[3] << 16)        - me1.z) * rs1.z + swishf(acc[6][r]);
        fn[7] = (asf(fo.u[3] & 0xffff0000u) - me1.w) * rs1.w + swishf(acc[7][r]);
        S8U o;
        o.u[0] = pk2(fn[0], fn[1]); o.u[1] = pk2(fn[2], fn[3]);
        o.u[2] = pk2(fn[4], fn[5]); o.u[3] = pk2(fn[6], fn[7]);
        *(short8*)(fB + (size_t)nd * 128 + lm * 8) = o.s;
#pragma unroll
        for (int t = 0; t < 8; t++) { ssum[t] += fn[t]; ssq[t] += fn[t] * fn[t]; }
    }
#pragma unroll
    for (int t = 0; t < 8; t++) {
        ssum[t] += __shfl_xor(ssum[t], 16); ssum[t] += __shfl_xor(ssum[t], 32);
        ssq[t]  += __shfl_xor(ssq[t], 16);  ssq[t]  += __shfl_xor(ssq[t], 32);
    }
    __syncthreads();
    float* red = (float*)lA;
    if (lq == 0) {
#pragma unroll
        for (int t = 0; t < 8; t++) {
            red[w * 256 + lm * 8 + t] = ssum[t];
            red[w * 256 + 128 + lm * 8 + t] = ssq[t];
        }
    }
    __syncthreads();
    {
        float v = red[tid] + red[256 + tid] + red[512 + tid] + red[768 + tid];
        partials[(size_t)blockIdx.x * 256 + tid] = v;
    }
}

// ---------- finalize: reduce 256 partials per batch -> meanrstd ----------
__global__ __launch_bounds__(256) void finalize_kernel(
    const float* __restrict__ partials, float* __restrict__ mr)
{
    __shared__ float s[256];
    int b = blockIdx.x, tid = threadIdx.x;
    float acc = 0.f;
    const float* p = partials + (size_t)b * 256 * 256 + tid;
#pragma unroll 8
    for (int i = 0; i < 256; i++) acc += p[i * 256];
    s[tid] = acc;
    __syncthreads();
    if (tid < 128) {
        float mean = s[tid] * (1.f / 16384.f);
        float var = s[128 + tid] * (1.f / 16384.f) - mean * mean;
        mr[b * 256 + tid] = mean;
        mr[b * 256 + 128 + tid] = rsqrtf(var + EPS);
    }
}

// ---------- output head ----------
__global__ __launch_bounds__(256) void out_head(
    const unsigned short* __restrict__ fB, const float* __restrict__ mr,
    const unsigned short* __restrict__ O1F, const float* __restrict__ ob1,
    const float* __restrict__ O2, const float* __restrict__ ob2,
    const float* __restrict__ u, float* __restrict__ out)
{
    __shared__ unsigned short lB[1024 * 8];
    int tid = threadIdx.x;
    int block0 = blockIdx.x * 64;
    int b = block0 >> 14;
    int w = tid >> 6, lane = tid & 63, lm = lane & 15, lq = lane >> 4;
#pragma unroll
    for (int i = 0; i < 4; i++)
        *(short8*)(lB + (tid + i * 256) * 8) = *(const short8*)(O1F + (tid + i * 256) * 8);
    short8 afr[4];
    build_normf_frags(fB, mr, block0, b, w, lm, lq, afr);
    float b1v[4], o2v[4];
#pragma unroll
    for (int t = 0; t < 4; t++) {
        b1v[t] = ob1[t * 16 + lm];
        o2v[t] = O2[t * 16 + lm];
    }
    __syncthreads();
    floatx4 acc[4];
#pragma unroll
    for (int t = 0; t < 4; t++) acc[t] = (floatx4)(b1v[t]);
#pragma unroll
    for (int ks = 0; ks < 4; ks++) {
#pragma unroll
        for (int t = 0; t < 4; t++) {
            short8 bf = *(const short8*)(lB + ((t * 4 + ks) * 64 + lane) * 8);
            acc[t] = __builtin_amdgcn_mfma_f32_16x16x32_bf16(afr[ks], bf, acc[t], 0, 0, 0);
        }
    }
    float ob2v = ob2[0];
#pragma unroll
    for (int r = 0; r < 4; r++) {
        float s = 0.f;
#pragma unroll
        for (int t = 0; t < 4; t++) s += swishf(acc[t][r]) * o2v[t];
        s += __shfl_xor(s, 1); s += __shfl_xor(s, 2);
        s += __shfl_xor(s, 4); s += __shfl_xor(s, 8);
        if (lm == 0) {
            int nd = block0 + w * 16 + lq * 4 + r;
            out[nd] = u[nd] + DT * (s + ob2v);
        }
    }
}

extern "C" void kernel_launch(void* const* d_in, const int* in_sizes, int n_in,
                              void* d_out, int out_size, void* d_ws, size_t ws_size,
                              hipStream_t stream)
{
    const float* inputs = (const float*)d_in[0];
    const float* cp     = (const float*)d_in[1];
    const float* emb_W1 = (const float*)d_in[3];
    const float* emb_b1 = (const float*)d_in[4];
    const float* emb_W2 = (const float*)d_in[5];
    const float* emb_b2 = (const float*)d_in[6];
    const float* msg1_W = (const float*)d_in[7];
    const float* msg1_b = (const float*)d_in[8];
    const float* msg2_W = (const float*)d_in[9];
    const float* msg2_b = (const float*)d_in[10];
    const float* upd1_W = (const float*)d_in[11];
    const float* upd1_b = (const float*)d_in[12];
    const float* upd2_W = (const float*)d_in[13];
    const float* upd2_b = (const float*)d_in[14];
    const float* out_W1 = (const float*)d_in[15];
    const float* out_b1 = (const float*)d_in[16];
    const float* out_W2 = (const float*)d_in[17];
    const float* out_b2 = (const float*)d_in[18];
    float* out = (float*)d_out;

    char* base = (char*)d_ws;
    size_t off = 0;
    unsigned short* fB   = (unsigned short*)(base + off); off += (size_t)NNODE * 128 * 2;
    unsigned short* Pn   = (unsigned short*)(base + off); off += (size_t)NNODE * 128 * 2;
    unsigned short* Qn   = (unsigned short*)(base + off); off += (size_t)NNODE * 128 * 2;
    unsigned short* aggF = (unsigned short*)(base + off); off += (size_t)NNODE * 128 * 2;
    float* u    = (float*)(base + off); off += NNODE * 4;
    float* posx = (float*)(base + off); off += NNODE * 4;
    float* posy = (float*)(base + off); off += NNODE * 4;
    float* partials = (float*)(base + off); off += 1024 * 256 * 4;
    float* mrbuf = (float*)(base + off); off += 1024 * 4;
    unsigned short* wPT  = (unsigned short*)(base + off); off += 6 * 16384 * 2;
    unsigned short* wQT  = (unsigned short*)(base + off); off += 6 * 16384 * 2;
    unsigned short* w2F  = (unsigned short*)(base + off); off += 6 * 16384 * 2;
    unsigned short* u1aF = (unsigned short*)(base + off); off += 6 * 16384 * 2;
    unsigned short* u1bF = (unsigned short*)(base + off); off += 6 * 16384 * 2;
    unsigned short* u2F  = (unsigned short*)(base + off); off += 6 * 16384 * 2;
    unsigned short* eW2F = (unsigned short*)(base + off); off += 16384 * 2;
    unsigned short* O1F  = (unsigned short*)(base + off); off += 8192 * 2;

    prep_all<<<2400, 256, 0, stream>>>(msg1_W, msg2_W, upd1_W, upd2_W, emb_W2, out_W1,
                                       wPT, wQT, w2F, u1aF, u1bF, u2F, eW2F, O1F);
    embed_mfma<<<1024, 256, 0, stream>>>(inputs, cp, emb_W1, emb_b1, eW2F, emb_b2,
                                         fB, u, posx, posy, mrbuf);
    for (int l = 0; l < 6; l++) {
        pqu_kernel<<<1024, 256, 0, stream>>>(fB, mrbuf,
            wPT + (size_t)l * 16384, wQT + (size_t)l * 16384,
            msg1_W + (size_t)l * 264 * 128, msg1_b + (size_t)l * 128,
            u, posx, posy, cp, Pn, Qn);
        msg_kernel<<<8192, 256, 0, stream>>>(Pn, Qn,
            w2F + (size_t)l * 16384, msg2_b + (size_t)l * 128, aggF);
        updf_kernel<<<1024, 256, 0, stream>>>(fB, mrbuf, aggF,
            u1aF + (size_t)l * 16384, u1bF + (size_t)l * 16384, u2F + (size_t)l * 16384,
            upd1_W + (size_t)l * 261 * 128, upd1_b + (size_t)l * 128,
            upd2_b + (size_t)l * 128, cp, partials);
        finalize_kernel<<<4, 256, 0, stream>>>(partials, mrbuf);
    }
    out_head<<<1024, 256, 0, stream>>>(fB, mrbuf, O1F, out_b1, out_W2, out_b2, u, out);
}

// Round 13
// 708.454 us; speedup vs baseline: 1.8286x; 1.0035x over previous
//
#include <hip/hip_runtime.h>
#include <hip/hip_bf16.h>
#include <hip/hip_fp16.h>
#include <math.h>

#define NNODE 65536
#define NBAT  16384
#define NP    5
#define DT    0.1f
#define EPS   1e-5f

typedef __attribute__((ext_vector_type(8))) short short8;
typedef __attribute__((ext_vector_type(4))) float floatx4;
typedef __attribute__((ext_vector_type(8))) _Float16 h8v;

union S8U { short8 s; unsigned int u[4]; };
union SH8 { short8 s; h8v h; };

// fast swish: x * rcp(1+e^-x)
__device__ __forceinline__ float swishf(float x) {
    return x * __builtin_amdgcn_rcpf(1.f + __expf(-x));
}
__device__ __forceinline__ float asf(unsigned int u) {
    union { unsigned int u; float f; } x; x.u = u; return x.f;
}
__device__ __forceinline__ unsigned short f2b(float f) {
    union { float f; unsigned int u; } x; x.f = f;
    unsigned int r = x.u + 0x7fff + ((x.u >> 16) & 1);
    return (unsigned short)(r >> 16);
}
__device__ __forceinline__ unsigned int pk2(float a, float b) {
    __hip_bfloat162 h = __float22bfloat162_rn(make_float2(a, b));
    union { __hip_bfloat162 h; unsigned int u; } x; x.h = h; return x.u;
}
// packed f16: pack two f32 -> f16x2 (v_cvt_pkrtz)
__device__ __forceinline__ unsigned int pkh(float a, float b) {
    union { __fp16 __attribute__((ext_vector_type(2))) h; unsigned int u; } x;
    x.h = __builtin_amdgcn_cvt_pkrtz(a, b);
    return x.u;
}
// packed f16 swish(P+Q)
__device__ __forceinline__ unsigned int h2swish_add(unsigned int pu, unsigned int qu) {
    union { unsigned int u; __half2 h; } p, q, r;
    p.u = pu; q.u = qu;
    __half2 t = __hadd2(p.h, q.h);
    __half2 e = h2exp(__hneg2(t));
    __half2 s = __hadd2(e, __float2half2_rn(1.f));
    r.h = __hmul2(t, h2rcp(s));
    return r.u;
}

// padded fragment chunk offset (in shorts)
#define CHP(w, g, r15) ((((w) * 272) + (g) * 17 + (r15)) * 8)

// ---------- fused weight prep: all matrices in one launch ----------
__global__ __launch_bounds__(256) void prep_all(
    const float* __restrict__ msg1_W, const float* __restrict__ msg2_W,
    const float* __restrict__ upd1_W, const float* __restrict__ upd2_W,
    const float* __restrict__ emb_W2, const float* __restrict__ out_W1,
    unsigned short* __restrict__ wPT, unsigned short* __restrict__ wQT,
    unsigned short* __restrict__ w2F, unsigned short* __restrict__ u1aF,
    unsigned short* __restrict__ u1bF, unsigned short* __restrict__ u2F,
    unsigned short* __restrict__ eW2F, unsigned short* __restrict__ O1F)
{
    int blk = blockIdx.x;
    const float* src; unsigned short* dst;
    int ldn = 128, koff, NT = 8, lstride, perm = 1, f16 = 0, i0;
    if (blk < 384)       { src = msg1_W; dst = wPT;  koff = 0;   lstride = 264 * 128; i0 = blk; }
    else if (blk < 768)  { src = msg1_W; dst = wQT;  koff = 128; lstride = 264 * 128; i0 = blk - 384; }
    else if (blk < 1152) { src = msg2_W; dst = w2F;  koff = 0;   lstride = 128 * 128; f16 = 1; i0 = blk - 768; }
    else if (blk < 1536) { src = upd1_W; dst = u1aF; koff = 0;   lstride = 261 * 128; i0 = blk - 1152; }
    else if (blk < 1920) { src = upd1_W; dst = u1bF; koff = 128; lstride = 261 * 128; i0 = blk - 1536; }
    else if (blk < 2304) { src = upd2_W; dst = u2F;  koff = 0;   lstride = 128 * 128; i0 = blk - 1920; }
    else if (blk < 2368) { src = emb_W2; dst = eW2F; koff = 0;   lstride = 0; perm = 0; i0 = blk - 2304; }
    else                 { src = out_W1; dst = O1F;  koff = 0;   lstride = 0; ldn = 64; NT = 4; i0 = blk - 2368; }
    int i = i0 * 256 + threadIdx.x;
    int nper = NT << 11;
    int l = i / nper;
    int r0 = i - l * nper;
    int t = r0 >> 11;
    int ks = (r0 >> 9) & 3;
    int lane = (r0 >> 3) & 63;
    int j = r0 & 7;
    int lm = lane & 15, lq = lane >> 4;
    int p = ks * 32 + lq * 8 + j;
    int k = perm ? ((p & 7) * 16 + (p >> 3)) : p;
    int n = t * 16 + lm;
    float val = src[(size_t)l * lstride + (size_t)(koff + k) * ldn + n];
    if (f16) {
        _Float16 h = (_Float16)val;
        dst[i] = *(unsigned short*)&h;
    } else {
        dst[i] = f2b(val);
    }
}

// ---------- build normalized-f A fragments in registers (f stored bf16 p-space) ----------
__device__ __forceinline__ void build_normf_frags(
    const unsigned short* __restrict__ fB, const float* __restrict__ mr,
    int block0, int b, int w, int lm, int lq, short8* afr)
{
    int row = block0 + w * 16 + lm;
#pragma unroll
    for (int ks = 0; ks < 4; ks++) {
        int po = ks * 32 + lq * 8;
        S8U v; v.s = *(const short8*)(fB + (size_t)row * 128 + po);
        float4 m0 = *(const float4*)(mr + b * 256 + po);
        float4 m1 = *(const float4*)(mr + b * 256 + po + 4);
        float4 s0 = *(const float4*)(mr + b * 256 + 128 + po);
        float4 s1 = *(const float4*)(mr + b * 256 + 128 + po + 4);
        S8U o;
        o.u[0] = pk2((asf(v.u[0] << 16) - m0.x) * s0.x,
                     (asf(v.u[0] & 0xffff0000u) - m0.y) * s0.y);
        o.u[1] = pk2((asf(v.u[1] << 16) - m0.z) * s0.z,
                     (asf(v.u[1] & 0xffff0000u) - m0.w) * s0.w);
        o.u[2] = pk2((asf(v.u[2] << 16) - m1.x) * s1.x,
                     (asf(v.u[2] & 0xffff0000u) - m1.y) * s1.y);
        o.u[3] = pk2((asf(v.u[3] << 16) - m1.z) * s1.z,
                     (asf(v.u[3] & 0xffff0000u) - m1.w) * s1.w);
        afr[ks] = o.s;
    }
}

// ---------- embedding (+ node scalars + mr init): 8 -> 128 -> 128 ----------
__global__ __launch_bounds__(256) void embed_mfma(
    const float* __restrict__ inp, const float* __restrict__ cp,
    const float* __restrict__ W1, const float* __restrict__ b1,
    const unsigned short* __restrict__ W2F, const float* __restrict__ b2,
    unsigned short* __restrict__ fB, float* __restrict__ u,
    float* __restrict__ posx, float* __restrict__ posy, float* __restrict__ mr)
{
    __shared__ unsigned short lA[4 * 272 * 8];
    __shared__ unsigned short lB[1024 * 8];
    int tid = threadIdx.x;
    int block0 = blockIdx.x * 64;
    if (blockIdx.x < 4) mr[blockIdx.x * 256 + tid] = ((tid >> 7) & 1) ? 1.f : 0.f;
    {
        int r = tid >> 2, p4 = tid & 3;
        int n = block0 + r;
        int b = n >> 14;
        int rr = n & 16383;
        int aa = rr >> 7, cc = rr & 127;
        float uu = inp[b * 3 * NBAT + rr];
        float pxx = (aa * (1.f / 127.f)) * cp[b * NP + 1];
        float pyy = (cc * (1.f / 127.f)) * cp[b * NP + 0];
        if (p4 == 0) { u[n] = uu; posx[n] = pxx; posy[n] = pyy; }
        float e8[8];
        e8[0] = uu; e8[1] = pxx; e8[2] = pyy;
#pragma unroll
        for (int p = 0; p < 5; p++) e8[3 + p] = cp[b * NP + p];
        float a32[32];
        const float4* b4 = (const float4*)(b1 + p4 * 32);
#pragma unroll
        for (int q = 0; q < 8; q++) {
            float4 bv = b4[q];
            a32[q * 4 + 0] = bv.x; a32[q * 4 + 1] = bv.y;
            a32[q * 4 + 2] = bv.z; a32[q * 4 + 3] = bv.w;
        }
#pragma unroll
        for (int i = 0; i < 8; i++) {
            const float4* w4 = (const float4*)(W1 + i * 128 + p4 * 32);
            float ev = e8[i];
#pragma unroll
            for (int q = 0; q < 8; q++) {
                float4 wv = w4[q];
                a32[q * 4 + 0] += ev * wv.x; a32[q * 4 + 1] += ev * wv.y;
                a32[q * 4 + 2] += ev * wv.z; a32[q * 4 + 3] += ev * wv.w;
            }
        }
#pragma unroll
        for (int j = 0; j < 4; j++) {
            S8U o;
#pragma unroll
            for (int q = 0; q < 4; q++)
                o.u[q] = pk2(swishf(a32[j * 8 + 2 * q]), swishf(a32[j * 8 + 2 * q + 1]));
            *(short8*)(lA + CHP(r >> 4, p4 * 4 + j, r & 15)) = o.s;
        }
    }
    int w = tid >> 6, lane = tid & 63, lm = lane & 15, lq = lane >> 4;
    float bias2[8];
#pragma unroll
    for (int t = 0; t < 8; t++) bias2[t] = b2[t * 16 + lm];
    floatx4 acc[8];
#pragma unroll
    for (int t = 0; t < 8; t++) acc[t] = (floatx4)(bias2[t]);
    for (int th = 0; th < 2; th++) {
        if (th) __syncthreads();
#pragma unroll
        for (int i = 0; i < 4; i++)
            *(short8*)(lB + (tid + i * 256) * 8) =
                *(const short8*)(W2F + (th * 1024 + tid + i * 256) * 8);
        __syncthreads();
#pragma unroll
        for (int ks = 0; ks < 4; ks++) {
            short8 a = *(const short8*)(lA + CHP(w, ks * 4 + lq, lm));
#pragma unroll
            for (int t2 = 0; t2 < 4; t2++) {
                short8 bf = *(const short8*)(lB + ((t2 * 4 + ks) * 64 + lane) * 8);
                acc[th * 4 + t2] = __builtin_amdgcn_mfma_f32_16x16x32_bf16(a, bf, acc[th * 4 + t2], 0, 0, 0);
            }
        }
    }
#pragma unroll
    for (int r = 0; r < 4; r++) {
        int nd = block0 + w * 16 + lq * 4 + r;
        S8U o;
        o.u[0] = pk2(swishf(acc[0][r]), swishf(acc[1][r]));
        o.u[1] = pk2(swishf(acc[2][r]), swishf(acc[3][r]));
        o.u[2] = pk2(swishf(acc[4][r]), swishf(acc[5][r]));
        o.u[3] = pk2(swishf(acc[6][r]), swishf(acc[7][r]));
        *(short8*)(fB + (size_t)nd * 128 + lm * 8) = o.s;
    }
}

// ---------- pqu: A-frags in regs (norm f bf16); P/Q phases; f16 P/Q out ----------
__global__ __launch_bounds__(256) void pqu_kernel(
    const unsigned short* __restrict__ fB, const float* __restrict__ mr,
    const unsigned short* __restrict__ wPT, const unsigned short* __restrict__ wQT,
    const float* __restrict__ mW, const float* __restrict__ mb,
    const float* __restrict__ u, const float* __restrict__ px,
    const float* __restrict__ py, const float* __restrict__ cp,
    unsigned short* __restrict__ Pn, unsigned short* __restrict__ Qn)
{
    __shared__ unsigned short lB[2048 * 8];
    int tid = threadIdx.x;
    int block0 = blockIdx.x * 64;
    int b = block0 >> 14;
    int w = tid >> 6, lane = tid & 63, lm = lane & 15, lq = lane >> 4;

    short8 afr[4];
    build_normf_frags(fB, mr, block0, b, w, lm, lq, afr);

    float u4[4], px4[4], py4[4];
#pragma unroll
    for (int r = 0; r < 4; r++) {
        int nd = block0 + w * 16 + lq * 4 + r;
        u4[r] = u[nd]; px4[r] = px[nd]; py4[r] = py[nd];
    }
    float cp5[5];
#pragma unroll
    for (int p = 0; p < 5; p++) cp5[p] = cp[b * NP + p];
    float wu[8], wx[8], wy[8], pt[8];
#pragma unroll
    for (int t = 0; t < 8; t++) {
        int c = t * 16 + lm;
        wu[t] = mW[256 * 128 + c]; wx[t] = mW[257 * 128 + c]; wy[t] = mW[258 * 128 + c];
        float p0 = mb[c];
#pragma unroll
        for (int p = 0; p < 5; p++) p0 += cp5[p] * mW[(259 + p) * 128 + c];
        pt[t] = p0;
    }

    for (int ph = 0; ph < 2; ph++) {
        const unsigned short* bsrc = (ph == 0) ? wPT : wQT;
        if (ph) __syncthreads();
#pragma unroll
        for (int i = 0; i < 8; i++)
            *(short8*)(lB + (tid + i * 256) * 8) = *(const short8*)(bsrc + (tid + i * 256) * 8);
        __syncthreads();
        floatx4 acc[8];
#pragma unroll
        for (int t = 0; t < 8; t++) acc[t] = (ph == 0) ? (floatx4)(pt[t]) : (floatx4)(0.f);
#pragma unroll
        for (int ks = 0; ks < 4; ks++) {
#pragma unroll
            for (int t = 0; t < 8; t++) {
                short8 bf = *(const short8*)(lB + ((t * 4 + ks) * 64 + lane) * 8);
                acc[t] = __builtin_amdgcn_mfma_f32_16x16x32_bf16(afr[ks], bf, acc[t], 0, 0, 0);
            }
        }
        if (ph == 0) {
#pragma unroll
            for (int r = 0; r < 4; r++) {
                int nd = block0 + w * 16 + lq * 4 + r;
                float sc0 = u4[r], sc1 = px4[r], sc2 = py4[r];
                float v[8];
#pragma unroll
                for (int t = 0; t < 8; t++)
                    v[t] = acc[t][r] + sc0 * wu[t] + sc1 * wx[t] + sc2 * wy[t];
                S8U o;
#pragma unroll
                for (int q = 0; q < 4; q++) o.u[q] = pkh(v[2 * q], v[2 * q + 1]);
                *(short8*)(Pn + (size_t)nd * 128 + lm * 8) = o.s;
            }
        } else {
#pragma unroll
            for (int r = 0; r < 4; r++) {
                int nd = block0 + w * 16 + lq * 4 + r;
                float sc0 = u4[r], sc1 = px4[r], sc2 = py4[r];
                float v[8];
#pragma unroll
                for (int t = 0; t < 8; t++)
                    v[t] = acc[t][r] - (sc0 * wu[t] + sc1 * wx[t] + sc2 * wy[t]);
                S8U o;
#pragma unroll
                for (int q = 0; q < 4; q++) o.u[q] = pkh(v[2 * q], v[2 * q + 1]);
                *(short8*)(Qn + (size_t)nd * 128 + lm * 8) = o.s;
            }
        }
    }
}

// ---------- msg: f16 P/Q; packed-f16 hidden; f16 MFMA; interior fast path ----------
__global__ __launch_bounds__(256) void msg_kernel(
    const unsigned short* __restrict__ Pn, const unsigned short* __restrict__ Qn,
    const unsigned short* __restrict__ w2F, const float* __restrict__ b2,
    unsigned short* __restrict__ aggF)
{
    __shared__ unsigned short lB[1024 * 8];
    __shared__ unsigned short lAgg[8 * 128];
    int tid = threadIdx.x;
    int base = blockIdx.x * 8;
    int b = base >> 14;
    int a = (base >> 7) & 127;
    int c0 = base & 127;
    int w = tid >> 6, lane = tid & 63, lm = lane & 15, lq = lane >> 4;
    bool interior = (a > 0) & (a < 127) & (c0 > 0) & (c0 + 8 < 128);

    // build hidden A-fragments in registers: f16 packed swish(P[t]+Q[s])
    short8 afr[4];
    {
        int tl = lm >> 3, e = lm & 7;
        int idx = (e < 4) ? e : e + 1;
        int dx = idx / 3 - 1, dy = idx % 3 - 1;
        int cc = c0 + w * 2 + tl;
        int na = a + dx, nc = cc + dy;
        int t = base + w * 2 + tl;
        int s;
        if (interior) s = (b << 14) + (na << 7) + nc;
        else {
            bool valid = (na >= 0) & (na < 128) & (nc >= 0) & (nc < 128);
            s = valid ? ((b << 14) + (na << 7) + nc) : t;
        }
#pragma unroll
        for (int ks = 0; ks < 4; ks++) {
            int po = ks * 32 + lq * 8;
            S8U pv, qv, o;
            pv.s = *(const short8*)(Pn + (size_t)t * 128 + po);
            qv.s = *(const short8*)(Qn + (size_t)s * 128 + po);
#pragma unroll
            for (int q = 0; q < 4; q++)
                o.u[q] = h2swish_add(pv.u[q], qv.u[q]);
            afr[ks] = o.s;
        }
    }

    float b2v[8];
#pragma unroll
    for (int t = 0; t < 8; t++) b2v[t] = b2[t * 16 + lm];
    floatx4 acc[8];
#pragma unroll
    for (int t = 0; t < 8; t++) acc[t] = (floatx4)(b2v[t]);
    for (int th = 0; th < 2; th++) {
        if (th) __syncthreads();
#pragma unroll
        for (int i = 0; i < 4; i++)
            *(short8*)(lB + (tid + i * 256) * 8) =
                *(const short8*)(w2F + (th * 1024 + tid + i * 256) * 8);
        __syncthreads();
#pragma unroll
        for (int ks = 0; ks < 4; ks++) {
            SH8 ax; ax.s = afr[ks];
#pragma unroll
            for (int t2 = 0; t2 < 4; t2++) {
                SH8 bx; bx.s = *(const short8*)(lB + ((t2 * 4 + ks) * 64 + lane) * 8);
                acc[th * 4 + t2] = __builtin_amdgcn_mfma_f32_16x16x32_f16(ax.h, bx.h, acc[th * 4 + t2], 0, 0, 0);
            }
        }
    }

    // epilogue
    if (interior) {
        float ov[8];
#pragma unroll
        for (int t = 0; t < 8; t++) {
            float s01 = swishf(acc[t][0]) + swishf(acc[t][1])
                      + swishf(acc[t][2]) + swishf(acc[t][3]);
            ov[t] = s01 + __shfl_xor(s01, 16);
        }
        if ((lq & 1) == 0) {
            int tl = w * 2 + (lq >> 1);
            S8U o;
#pragma unroll
            for (int q = 0; q < 4; q++)
                o.u[q] = pk2(ov[2 * q] * 0.125f, ov[2 * q + 1] * 0.125f);
            *(short8*)(lAgg + tl * 128 + lm * 8) = o.s;
        }
    } else {
        bool vr[4];
#pragma unroll
        for (int r = 0; r < 4; r++) {
            int row16 = lq * 4 + r;
            int tl2 = row16 >> 3, e = row16 & 7;
            int idx = (e < 4) ? e : e + 1;
            int dx = idx / 3 - 1, dy = idx % 3 - 1;
            int cc = c0 + w * 2 + tl2;
            int na = a + dx, nc = cc + dy;
            vr[r] = (na >= 0) & (na < 128) & (nc >= 0) & (nc < 128);
        }
        float ov[8];
#pragma unroll
        for (int t = 0; t < 8; t++) {
            float s01 = 0.f;
#pragma unroll
            for (int r = 0; r < 4; r++)
                s01 += vr[r] ? swishf(acc[t][r]) : 0.f;
            ov[t] = s01 + __shfl_xor(s01, 16);
        }
        if ((lq & 1) == 0) {
            int tl = w * 2 + (lq >> 1);
            int cc = c0 + tl;
            int deg = (1 + (a > 0) + (a < 127)) * (1 + (cc > 0) + (cc < 127)) - 1;
            float inv = 1.f / (float)deg;
            S8U o;
#pragma unroll
            for (int q = 0; q < 4; q++) o.u[q] = pk2(ov[2 * q] * inv, ov[2 * q + 1] * inv);
            *(short8*)(lAgg + tl * 128 + lm * 8) = o.s;
        }
    }
    __syncthreads();
    if (tid < 128) {
        int row8 = tid >> 4, g = tid & 15;
        int n = base + row8;
        size_t lin = (size_t)(n >> 6) * 1024 + (size_t)(((n & 63) >> 4) * 256 + g * 16 + (n & 15));
        *(short8*)(aggF + lin * 8) = *(const short8*)(lAgg + row8 * 128 + g * 8);
    }
}

// ---------- updf: biases in acc; half-staged B; bf16 f; per-block partials ----------
__global__ __launch_bounds__(256) void updf_kernel(
    unsigned short* __restrict__ fB, const float* __restrict__ mr,
    const unsigned short* __restrict__ aggF,
    const unsigned short* __restrict__ u1aF, const unsigned short* __restrict__ u1bF,
    const unsigned short* __restrict__ u2F,
    const float* __restrict__ U1, const float* __restrict__ c1,
    const float* __restrict__ c2, const float* __restrict__ cp,
    float* __restrict__ partials)
{
    __shared__ unsigned short lA[4 * 272 * 8];   // hid (padded); later reduce buffer
    __shared__ unsigned short lB[1024 * 8];
    int tid = threadIdx.x;
    int block0 = blockIdx.x * 64;
    int b = block0 >> 14;
    int w = tid >> 6, lane = tid & 63, lm = lane & 15, lq = lane >> 4;

    float cp5[5];
#pragma unroll
    for (int p = 0; p < 5; p++) cp5[p] = cp[b * NP + p];
    float pt[8];
#pragma unroll
    for (int t = 0; t < 8; t++) {
        int c = t * 16 + lm;
        float p0 = c1[c];
#pragma unroll
        for (int p = 0; p < 5; p++) p0 += cp5[p] * U1[(256 + p) * 128 + c];
        pt[t] = p0;
    }

    short8 afr[4];
    build_normf_frags(fB, mr, block0, b, w, lm, lq, afr);
    floatx4 acc[8];
#pragma unroll
    for (int t = 0; t < 8; t++) acc[t] = (floatx4)(pt[t]);

    // phases 1 & 2: acc += normf @ U1a + agg @ U1b
    for (int ph = 0; ph < 2; ph++) {
        const unsigned short* bsrc = ph ? u1bF : u1aF;
        if (ph) {
#pragma unroll
            for (int ks = 0; ks < 4; ks++)
                afr[ks] = *(const short8*)(aggF +
                    ((size_t)blockIdx.x * 1024 + w * 256 + (ks * 4 + lq) * 16 + lm) * 8);
        }
        for (int th = 0; th < 2; th++) {
            if (ph | th) __syncthreads();
#pragma unroll
            for (int i = 0; i < 4; i++)
                *(short8*)(lB + (tid + i * 256) * 8) =
                    *(const short8*)(bsrc + (th * 1024 + tid + i * 256) * 8);
            __syncthreads();
#pragma unroll
            for (int ks = 0; ks < 4; ks++) {
#pragma unroll
                for (int t2 = 0; t2 < 4; t2++) {
                    short8 bf = *(const short8*)(lB + ((t2 * 4 + ks) * 64 + lane) * 8);
                    acc[th * 4 + t2] = __builtin_amdgcn_mfma_f32_16x16x32_bf16(afr[ks], bf, acc[th * 4 + t2], 0, 0, 0);
                }
            }
        }
    }

    // epi1: h = swish(acc) -> lA (padded)
#pragma unroll
    for (int r = 0; r < 4; r++) {
        S8U o;
#pragma unroll
        for (int q = 0; q < 4; q++)
            o.u[q] = pk2(swishf(acc[2 * q][r]), swishf(acc[2 * q + 1][r]));
        *(short8*)(lA + CHP(w, lm, lq * 4 + r)) = o.s;
    }

    // phase 3: acc = c2 + hid @ U2
    float c2v[8];
#pragma unroll
    for (int t = 0; t < 8; t++) c2v[t] = c2[t * 16 + lm];
#pragma unroll
    for (int t = 0; t < 8; t++) acc[t] = (floatx4)(c2v[t]);
    for (int th = 0; th < 2; th++) {
        __syncthreads();
#pragma unroll
        for (int i = 0; i < 4; i++)
            *(short8*)(lB + (tid + i * 256) * 8) =
                *(const short8*)(u2F + (th * 1024 + tid + i * 256) * 8);
        __syncthreads();
#pragma unroll
        for (int ks = 0; ks < 4; ks++) {
            short8 a = *(const short8*)(lA + CHP(w, ks * 4 + lq, lm));
#pragma unroll
            for (int t2 = 0; t2 < 4; t2++) {
                short8 bf = *(const short8*)(lB + ((t2 * 4 + ks) * 64 + lane) * 8);
                acc[th * 4 + t2] = __builtin_amdgcn_mfma_f32_16x16x32_bf16(a, bf, acc[th * 4 + t2], 0, 0, 0);
            }
        }
    }

    // epi2: fn = norm(f_old) + swish(acc); write f (bf16); partial stats
    float4 me0 = *(const float4*)(mr + b * 256 + lm * 8);
    float4 me1 = *(const float4*)(mr + b * 256 + lm * 8 + 4);
    float4 rs0 = *(const float4*)(mr + b * 256 + 128 + lm * 8);
    float4 rs1 = *(const float4*)(mr + b * 256 + 128 + lm * 8 + 4);
    float ssum[8], ssq[8];
#pragma unroll
    for (int t = 0; t < 8; t++) { ssum[t] = 0.f; ssq[t] = 0.f; }
#pragma unroll
    for (int r = 0; r < 4; r++) {
        int nd = block0 + w * 16 + lq * 4 + r;
        S8U fo; fo.s = *(const short8*)(fB + (size_t)nd * 128 + lm * 8);
        float fn[8];
        fn[0] = (asf(fo.u[0] << 16)        - me0.x) * rs0.x + swishf(acc[0][r]);
        fn[1] = (asf(fo.u[0] & 0xffff0000u) - me0.y) * rs0.y + swishf(acc[1][r]);
        fn[2] = (asf(fo.u[1] << 16)        - me0.z) * rs0.z + swishf(acc[2][r]);
        fn[3] = (asf(fo.u[1] & 0xffff0000u) - me0.w) * rs0.w + swishf(acc[3][r]);
        fn[4] = (asf(fo.u[2] << 16)        - me1.x) * rs1.x + swishf(acc[4][r]);
        fn[5] = (asf(fo.u[2] & 0xffff0000u) - me1.y) * rs1.y + swishf(acc[5][r]);
        fn[6] = (asf(fo.u[3] << 16)        - me1.z) * rs1.z + swishf(acc[6][r]);
        fn[7] = (asf(fo.u[3] & 0xffff0000u) - me1.w) * rs1.w + swishf(acc[7][r]);
        S8U o;
        o.u[0] = pk2(fn[0], fn[1]); o.u[1] = pk2(fn[2], fn[3]);
        o.u[2] = pk2(fn[4], fn[5]); o.u[3] = pk2(fn[6], fn[7]);
        *(short8*)(fB + (size_t)nd * 128 + lm * 8) = o.s;
#pragma unroll
        for (int t = 0; t < 8; t++) { ssum[t] += fn[t]; ssq[t] += fn[t] * fn[t]; }
    }
#pragma unroll
    for (int t = 0; t < 8; t++) {
        ssum[t] += __shfl_xor(ssum[t], 16); ssum[t] += __shfl_xor(ssum[t], 32);
        ssq[t]  += __shfl_xor(ssq[t], 16);  ssq[t]  += __shfl_xor(ssq[t], 32);
    }
    __syncthreads();
    float* red = (float*)lA;
    if (lq == 0) {
#pragma unroll
        for (int t = 0; t < 8; t++) {
            red[w * 256 + lm * 8 + t] = ssum[t];
            red[w * 256 + 128 + lm * 8 + t] = ssq[t];
        }
    }
    __syncthreads();
    {
        float v = red[tid] + red[256 + tid] + red[512 + tid] + red[768 + tid];
        partials[(size_t)blockIdx.x * 256 + tid] = v;
    }
}

// ---------- finalize: reduce 256 partials per batch -> meanrstd ----------
__global__ __launch_bounds__(256) void finalize_kernel(
    const float* __restrict__ partials, float* __restrict__ mr)
{
    __shared__ float s[256];
    int b = blockIdx.x, tid = threadIdx.x;
    float acc = 0.f;
    const float* p = partials + (size_t)b * 256 * 256 + tid;
#pragma unroll 8
    for (int i = 0; i < 256; i++) acc += p[i * 256];
    s[tid] = acc;
    __syncthreads();
    if (tid < 128) {
        float mean = s[tid] * (1.f / 16384.f);
        float var = s[128 + tid] * (1.f / 16384.f) - mean * mean;
        mr[b * 256 + tid] = mean;
        mr[b * 256 + 128 + tid] = rsqrtf(var + EPS);
    }
}

// ---------- output head ----------
__global__ __launch_bounds__(256) void out_head(
    const unsigned short* __restrict__ fB, const float* __restrict__ mr,
    const unsigned short* __restrict__ O1F, const float* __restrict__ ob1,
    const float* __restrict__ O2, const float* __restrict__ ob2,
    const float* __restrict__ u, float* __restrict__ out)
{
    __shared__ unsigned short lB[1024 * 8];
    int tid = threadIdx.x;
    int block0 = blockIdx.x * 64;
    int b = block0 >> 14;
    int w = tid >> 6, lane = tid & 63, lm = lane & 15, lq = lane >> 4;
#pragma unroll
    for (int i = 0; i < 4; i++)
        *(short8*)(lB + (tid + i * 256) * 8) = *(const short8*)(O1F + (tid + i * 256) * 8);
    short8 afr[4];
    build_normf_frags(fB, mr, block0, b, w, lm, lq, afr);
    float b1v[4], o2v[4];
#pragma unroll
    for (int t = 0; t < 4; t++) {
        b1v[t] = ob1[t * 16 + lm];
        o2v[t] = O2[t * 16 + lm];
    }
    __syncthreads();
    floatx4 acc[4];
#pragma unroll
    for (int t = 0; t < 4; t++) acc[t] = (floatx4)(b1v[t]);
#pragma unroll
    for (int ks = 0; ks < 4; ks++) {
#pragma unroll
        for (int t = 0; t < 4; t++) {
            short8 bf = *(const short8*)(lB + ((t * 4 + ks) * 64 + lane) * 8);
            acc[t] = __builtin_amdgcn_mfma_f32_16x16x32_bf16(afr[ks], bf, acc[t], 0, 0, 0);
        }
    }
    float ob2v = ob2[0];
#pragma unroll
    for (int r = 0; r < 4; r++) {
        float s = 0.f;
#pragma unroll
        for (int t = 0; t < 4; t++) s += swishf(acc[t][r]) * o2v[t];
        s += __shfl_xor(s, 1); s += __shfl_xor(s, 2);
        s += __shfl_xor(s, 4); s += __shfl_xor(s, 8);
        if (lm == 0) {
            int nd = block0 + w * 16 + lq * 4 + r;
            out[nd] = u[nd] + DT * (s + ob2v);
        }
    }
}

extern "C" void kernel_launch(void* const* d_in, const int* in_sizes, int n_in,
                              void* d_out, int out_size, void* d_ws, size_t ws_size,
                              hipStream_t stream)
{
    const float* inputs = (const float*)d_in[0];
    const float* cp     = (const float*)d_in[1];
    const float* emb_W1 = (const float*)d_in[3];
    const float* emb_b1 = (const float*)d_in[4];
    const float* emb_W2 = (const float*)d_in[5];
    const float* emb_b2 = (const float*)d_in[6];
    const float* msg1_W = (const float*)d_in[7];
    const float* msg1_b = (const float*)d_in[8];
    const float* msg2_W = (const float*)d_in[9];
    const float* msg2_b = (const float*)d_in[10];
    const float* upd1_W = (const float*)d_in[11];
    const float* upd1_b = (const float*)d_in[12];
    const float* upd2_W = (const float*)d_in[13];
    const float* upd2_b = (const float*)d_in[14];
    const float* out_W1 = (const float*)d_in[15];
    const float* out_b1 = (const float*)d_in[16];
    const float* out_W2 = (const float*)d_in[17];
    const float* out_b2 = (const float*)d_in[18];
    float* out = (float*)d_out;

    char* base = (char*)d_ws;
    size_t off = 0;
    unsigned short* fB   = (unsigned short*)(base + off); off += (size_t)NNODE * 128 * 2;
    unsigned short* Pn   = (unsigned short*)(base + off); off += (size_t)NNODE * 128 * 2;
    unsigned short* Qn   = (unsigned short*)(base + off); off += (size_t)NNODE * 128 * 2;
    unsigned short* aggF = (unsigned short*)(base + off); off += (size_t)NNODE * 128 * 2;
    float* u    = (float*)(base + off); off += NNODE * 4;
    float* posx = (float*)(base + off); off += NNODE * 4;
    float* posy = (float*)(base + off); off += NNODE * 4;
    float* partials = (float*)(base + off); off += 1024 * 256 * 4;
    float* mrbuf = (float*)(base + off); off += 1024 * 4;
    unsigned short* wPT  = (unsigned short*)(base + off); off += 6 * 16384 * 2;
    unsigned short* wQT  = (unsigned short*)(base + off); off += 6 * 16384 * 2;
    unsigned short* w2F  = (unsigned short*)(base + off); off += 6 * 16384 * 2;
    unsigned short* u1aF = (unsigned short*)(base + off); off += 6 * 16384 * 2;
    unsigned short* u1bF = (unsigned short*)(base + off); off += 6 * 16384 * 2;
    unsigned short* u2F  = (unsigned short*)(base + off); off += 6 * 16384 * 2;
    unsigned short* eW2F = (unsigned short*)(base + off); off += 16384 * 2;
    unsigned short* O1F  = (unsigned short*)(base + off); off += 8192 * 2;

    prep_all<<<2400, 256, 0, stream>>>(msg1_W, msg2_W, upd1_W, upd2_W, emb_W2, out_W1,
                                       wPT, wQT, w2F, u1aF, u1bF, u2F, eW2F, O1F);
    embed_mfma<<<1024, 256, 0, stream>>>(inputs, cp, emb_W1, emb_b1, eW2F, emb_b2,
                                         fB, u, posx, posy, mrbuf);
    for (int l = 0; l < 6; l++) {
        pqu_kernel<<<1024, 256, 0, stream>>>(fB, mrbuf,
            wPT + (size_t)l * 16384, wQT + (size_t)l * 16384,
            msg1_W + (size_t)l * 264 * 128, msg1_b + (size_t)l * 128,
            u, posx, posy, cp, Pn, Qn);
        msg_kernel<<<8192, 256, 0, stream>>>(Pn, Qn,
            w2F + (size_t)l * 16384, msg2_b + (size_t)l * 128, aggF);
        updf_kernel<<<1024, 256, 0, stream>>>(fB, mrbuf, aggF,
            u1aF + (size_t)l * 16384, u1bF + (size_t)l * 16384, u2F + (size_t)l * 16384,
            upd1_W + (size_t)l * 261 * 128, upd1_b + (size_t)l * 128,
            upd2_b + (size_t)l * 128, cp, partials);
        finalize_kernel<<<4, 256, 0, stream>>>(partials, mrbuf);
    }
    out_head<<<1024, 256, 0, stream>>>(fB, mrbuf, O1F, out_b1, out_W2, out_b2, u, out);
}